// Round 1
// baseline (1134.663 us; speedup 1.0000x reference)
//
#include <hip/hip_runtime.h>
#include <hip/hip_bf16.h>
#include <math.h>

// Problem constants
#define B_ 2
#define S_ 2048
#define H_ 1024
#define A_ 1024
#define NH_ 16
#define HD_ 64
#define H3_ 3072
#define EPS_ 1e-5f

// ---------------------------------------------------------------------------
// Kernel 1: mod = silu(ada_cond) @ mod_w^T + mod_b     [B, 3H]
// one wave per output element
// ---------------------------------------------------------------------------
__global__ __launch_bounds__(256) void mod_gemv_kernel(
    const float* __restrict__ ada, const float* __restrict__ mod_w,
    const float* __restrict__ mod_b, float* __restrict__ mod)
{
    int wid = threadIdx.x >> 6;
    int lane = threadIdx.x & 63;
    int idx = blockIdx.x * 4 + wid;       // 0 .. B*3H-1
    int b = idx / H3_;
    int j = idx % H3_;
    const float* ar = ada + (size_t)b * A_;
    const float* wr = mod_w + (size_t)j * A_;
    float acc = 0.f;
    for (int a = lane; a < A_; a += 64) {
        float av = ar[a];
        float sv = av / (1.f + __expf(-av));   // silu
        acc += sv * wr[a];
    }
    #pragma unroll
    for (int m = 1; m < 64; m <<= 1) acc += __shfl_xor(acc, m);
    if (lane == 0) mod[idx] = acc + mod_b[j];
}

// ---------------------------------------------------------------------------
// Kernel 2: h = layernorm(x)*ln_w * (scale+1) + shift   [B,S,H], one block/row
// ---------------------------------------------------------------------------
__global__ __launch_bounds__(256) void ln_mod_kernel(
    const float* __restrict__ x, const float* __restrict__ ln_w,
    const float* __restrict__ mod, float* __restrict__ hout)
{
    int row = blockIdx.x;          // over B*S
    int b = row >> 11;             // row / 2048
    const float* xr = x + (size_t)row * H_;
    int t = threadIdx.x;
    float4 xv = *(const float4*)(xr + t * 4);
    float s1 = xv.x + xv.y + xv.z + xv.w;
    float s2 = xv.x*xv.x + xv.y*xv.y + xv.z*xv.z + xv.w*xv.w;
    #pragma unroll
    for (int m = 1; m < 64; m <<= 1) { s1 += __shfl_xor(s1, m); s2 += __shfl_xor(s2, m); }
    __shared__ float r1[4], r2[4];
    int wid = t >> 6, lane = t & 63;
    if (lane == 0) { r1[wid] = s1; r2[wid] = s2; }
    __syncthreads();
    s1 = r1[0] + r1[1] + r1[2] + r1[3];
    s2 = r2[0] + r2[1] + r2[2] + r2[3];
    float mean = s1 * (1.f / H_);
    float var  = s2 * (1.f / H_) - mean * mean;
    float rstd = rsqrtf(var + EPS_);
    const float* mrow = mod + (size_t)b * H3_;
    float4 wv = *(const float4*)(ln_w + t * 4);
    float4 sc = *(const float4*)(mrow + t * 4);
    float4 sh = *(const float4*)(mrow + H_ + t * 4);
    float4 hv;
    hv.x = (xv.x - mean) * rstd * wv.x * (sc.x + 1.f) + sh.x;
    hv.y = (xv.y - mean) * rstd * wv.y * (sc.y + 1.f) + sh.y;
    hv.z = (xv.z - mean) * rstd * wv.z * (sc.z + 1.f) + sh.z;
    hv.w = (xv.w - mean) * rstd * wv.w * (sc.w + 1.f) + sh.w;
    *(float4*)(hout + (size_t)row * H_ + t * 4) = hv;
}

// ---------------------------------------------------------------------------
// Kernel 3/6: C[M,N] = A[M,K] @ B[N,K]^T  (both K-contiguous), fp32 tiled.
// 64x64 tile, 256 threads, 4x4 micro-tile. Optional per-(batch,col) gate.
// ---------------------------------------------------------------------------
#define BM 64
#define BN 64
#define BK 16
__global__ __launch_bounds__(256) void gemm_nt_kernel(
    const float* __restrict__ A, const float* __restrict__ Bm,
    float* __restrict__ C, int M, int N, int K,
    const float* __restrict__ gate, int gate_stride, int rows_per_batch)
{
    __shared__ float As[BK][BM + 4];
    __shared__ float Bs[BK][BN + 4];
    int t = threadIdx.x;
    int tx = t & 15, ty = t >> 4;
    int m0 = blockIdx.y * BM, n0 = blockIdx.x * BN;
    int lrow = t >> 2;            // 0..63
    int lk4 = (t & 3) * 4;        // 0,4,8,12
    float acc[4][4] = {};
    for (int k0 = 0; k0 < K; k0 += BK) {
        float4 a4 = *(const float4*)(A + (size_t)(m0 + lrow) * K + k0 + lk4);
        float4 b4 = *(const float4*)(Bm + (size_t)(n0 + lrow) * K + k0 + lk4);
        As[lk4 + 0][lrow] = a4.x; As[lk4 + 1][lrow] = a4.y;
        As[lk4 + 2][lrow] = a4.z; As[lk4 + 3][lrow] = a4.w;
        Bs[lk4 + 0][lrow] = b4.x; Bs[lk4 + 1][lrow] = b4.y;
        Bs[lk4 + 2][lrow] = b4.z; Bs[lk4 + 3][lrow] = b4.w;
        __syncthreads();
        #pragma unroll
        for (int k = 0; k < BK; ++k) {
            float4 af = *(const float4*)&As[k][ty * 4];
            float4 bf = *(const float4*)&Bs[k][tx * 4];
            float ar[4] = {af.x, af.y, af.z, af.w};
            float br[4] = {bf.x, bf.y, bf.z, bf.w};
            #pragma unroll
            for (int i = 0; i < 4; ++i)
                #pragma unroll
                for (int j = 0; j < 4; ++j)
                    acc[i][j] += ar[i] * br[j];
        }
        __syncthreads();
    }
    #pragma unroll
    for (int i = 0; i < 4; ++i) {
        int m = m0 + ty * 4 + i;
        #pragma unroll
        for (int j = 0; j < 4; ++j) {
            int n = n0 + tx * 4 + j;
            float v = acc[i][j];
            if (gate) v *= gate[(m / rows_per_batch) * gate_stride + n];
            C[(size_t)m * N + n] = v;
        }
    }
}

// ---------------------------------------------------------------------------
// Kernel 4: per-head QK layernorm + RoPE; scatter q,k,v to [bh, S, 64]
// one wave per (b,h,s) row
// ---------------------------------------------------------------------------
__global__ __launch_bounds__(256) void qk_ln_rope_kernel(
    const float* __restrict__ qkv, const float* __restrict__ freqs,
    const float* __restrict__ qn_w, const float* __restrict__ kn_w,
    float* __restrict__ qout, float* __restrict__ kout, float* __restrict__ vout)
{
    int wid = threadIdx.x >> 6;
    int lane = threadIdx.x & 63;
    int row = blockIdx.x * 4 + wid;       // over B*nh*S
    int s = row & (S_ - 1);
    int bh = row >> 11;
    int h = bh & (NH_ - 1);
    int b = bh >> 4;
    const float* base = qkv + ((size_t)(b * S_ + s)) * H3_;
    float qv = base[h * HD_ + lane];
    float kv = base[H_ + h * HD_ + lane];
    float vv = base[2 * H_ + h * HD_ + lane];

    // layernorm over 64 lanes
    float qs1 = qv, qs2 = qv * qv, ks1 = kv, ks2 = kv * kv;
    #pragma unroll
    for (int m = 1; m < 64; m <<= 1) {
        qs1 += __shfl_xor(qs1, m); qs2 += __shfl_xor(qs2, m);
        ks1 += __shfl_xor(ks1, m); ks2 += __shfl_xor(ks2, m);
    }
    float qm = qs1 * (1.f / 64), qvar = qs2 * (1.f / 64) - qm * qm;
    float km = ks1 * (1.f / 64), kvar = ks2 * (1.f / 64) - km * km;
    qv = (qv - qm) * rsqrtf(qvar + EPS_) * qn_w[lane];
    kv = (kv - km) * rsqrtf(kvar + EPS_) * kn_w[lane];

    // RoPE: interleaved pairs (2i, 2i+1)
    float f0 = freqs[(size_t)s * 64 + (lane >> 1) * 2 + 0];
    float f1 = freqs[(size_t)s * 64 + (lane >> 1) * 2 + 1];
    float qp = __shfl_xor(qv, 1);
    float kp = __shfl_xor(kv, 1);
    float qr = (lane & 1) ? (qv * f0 + qp * f1) : (qv * f0 - qp * f1);
    float kr = (lane & 1) ? (kv * f0 + kp * f1) : (kv * f0 - kp * f1);

    size_t o = ((size_t)bh * S_ + s) * HD_ + lane;
    qout[o] = qr; kout[o] = kr; vout[o] = vv;
}

// ---------------------------------------------------------------------------
// Kernel 5: flash attention. Block = (bh, 64-query tile). K/V tiles of 64.
// Writes output directly in [B,S,H] layout.
// ---------------------------------------------------------------------------
__global__ __launch_bounds__(256) void attn_kernel(
    const float* __restrict__ q, const float* __restrict__ k,
    const float* __restrict__ v, float* __restrict__ o)
{
    __shared__ float Qs[64][68];   // Qs[d][query]  (transposed, pre-scaled)
    __shared__ float Ks[64][68];   // Ks[d][key]
    __shared__ float Ps[64][68];   // Ps[key][query]
    __shared__ float Vs[64][64];   // Vs[key][d]

    int bh = blockIdx.y;
    int b = bh >> 4, h = bh & 15;
    int s0 = blockIdx.x * 64;
    int t = threadIdx.x, tx = t & 15, ty = t >> 4;

    const float* qg = q + ((size_t)bh * S_ + s0) * HD_;
    for (int i = t; i < 4096; i += 256) {
        int r = i >> 6, d = i & 63;
        Qs[d][r] = qg[i] * 0.125f;   // 1/sqrt(64) folded into Q
    }

    float m_i[4], l_i[4], acc[4][4];
    #pragma unroll
    for (int i = 0; i < 4; ++i) {
        m_i[i] = -3.0e38f; l_i[i] = 0.f;
        #pragma unroll
        for (int j = 0; j < 4; ++j) acc[i][j] = 0.f;
    }

    for (int kt = 0; kt < S_ / 64; ++kt) {
        __syncthreads();
        const float* kg = k + ((size_t)bh * S_ + kt * 64) * HD_;
        const float* vg = v + ((size_t)bh * S_ + kt * 64) * HD_;
        for (int i = t; i < 4096; i += 256) {
            int r = i >> 6, d = i & 63;
            Ks[d][r] = kg[i];
            Vs[r][d] = vg[i];
        }
        __syncthreads();

        float sc[4][4] = {};
        #pragma unroll 8
        for (int d = 0; d < 64; ++d) {
            float4 qa = *(const float4*)&Qs[d][ty * 4];
            float4 kb = *(const float4*)&Ks[d][tx * 4];
            float qr[4] = {qa.x, qa.y, qa.z, qa.w};
            float kr[4] = {kb.x, kb.y, kb.z, kb.w};
            #pragma unroll
            for (int i = 0; i < 4; ++i)
                #pragma unroll
                for (int j = 0; j < 4; ++j)
                    sc[i][j] += qr[i] * kr[j];
        }

        // online softmax (row reductions across the 16 tx lanes)
        #pragma unroll
        for (int i = 0; i < 4; ++i) {
            float mx = fmaxf(fmaxf(sc[i][0], sc[i][1]), fmaxf(sc[i][2], sc[i][3]));
            #pragma unroll
            for (int msk = 1; msk < 16; msk <<= 1) mx = fmaxf(mx, __shfl_xor(mx, msk, 16));
            float mnew = fmaxf(m_i[i], mx);
            float alpha = __expf(m_i[i] - mnew);
            m_i[i] = mnew;
            float rs = 0.f;
            #pragma unroll
            for (int j = 0; j < 4; ++j) {
                float p = __expf(sc[i][j] - mnew);
                sc[i][j] = p;
                rs += p;
            }
            #pragma unroll
            for (int msk = 1; msk < 16; msk <<= 1) rs += __shfl_xor(rs, msk, 16);
            l_i[i] = l_i[i] * alpha + rs;
            #pragma unroll
            for (int j = 0; j < 4; ++j) {
                acc[i][j] *= alpha;
                Ps[tx * 4 + j][ty * 4 + i] = sc[i][j];
            }
        }
        __syncthreads();

        // O += P @ V
        #pragma unroll 8
        for (int kk = 0; kk < 64; ++kk) {
            float4 pa = *(const float4*)&Ps[kk][ty * 4];
            float4 vb = *(const float4*)&Vs[kk][tx * 4];
            float pr[4] = {pa.x, pa.y, pa.z, pa.w};
            float vr[4] = {vb.x, vb.y, vb.z, vb.w};
            #pragma unroll
            for (int i = 0; i < 4; ++i)
                #pragma unroll
                for (int j = 0; j < 4; ++j)
                    acc[i][j] += pr[i] * vr[j];
        }
    }

    // epilogue: normalize and scatter to [B,S,H]
    float* og = o + ((size_t)(b * S_ + s0)) * H_ + h * HD_;
    #pragma unroll
    for (int i = 0; i < 4; ++i) {
        float inv = 1.f / l_i[i];
        #pragma unroll
        for (int j = 0; j < 4; ++j)
            og[(size_t)(ty * 4 + i) * H_ + tx * 4 + j] = acc[i][j] * inv;
    }
}

// ---------------------------------------------------------------------------
extern "C" void kernel_launch(void* const* d_in, const int* in_sizes, int n_in,
                              void* d_out, int out_size, void* d_ws, size_t ws_size,
                              hipStream_t stream)
{
    const float* x     = (const float*)d_in[0];
    const float* ada   = (const float*)d_in[1];
    const float* freqs = (const float*)d_in[2];
    const float* w_qkv = (const float*)d_in[3];
    const float* w_o   = (const float*)d_in[4];
    const float* ln_w  = (const float*)d_in[5];
    const float* mod_w = (const float*)d_in[6];
    const float* mod_b = (const float*)d_in[7];
    const float* qn_w  = (const float*)d_in[8];
    const float* kn_w  = (const float*)d_in[9];
    float* out = (float*)d_out;

    float* ws  = (float*)d_ws;
    float* mod = ws;                              // B*3H          = 6144
    float* h   = mod + B_ * H3_;                  // B*S*H         = 4194304
    float* qkv = h + (size_t)B_ * S_ * H_;        // B*S*3H        = 12582912
    float* qb  = qkv + (size_t)B_ * S_ * H3_;     // B*nh*S*hd     = 4194304
    float* kb  = qb + (size_t)B_ * S_ * H_;
    float* vb  = kb + (size_t)B_ * S_ * H_;
    float* ob  = h;                               // reuse h for attention out

    mod_gemv_kernel<<<B_ * H3_ / 4, 256, 0, stream>>>(ada, mod_w, mod_b, mod);
    ln_mod_kernel<<<B_ * S_, 256, 0, stream>>>(x, ln_w, mod, h);
    gemm_nt_kernel<<<dim3(H3_ / BN, B_ * S_ / BM), 256, 0, stream>>>(
        h, w_qkv, qkv, B_ * S_, H3_, H_, nullptr, 0, 1);
    qk_ln_rope_kernel<<<B_ * NH_ * S_ / 4, 256, 0, stream>>>(
        qkv, freqs, qn_w, kn_w, qb, kb, vb);
    attn_kernel<<<dim3(S_ / 64, B_ * NH_), 256, 0, stream>>>(qb, kb, vb, ob);
    gemm_nt_kernel<<<dim3(H_ / BN, B_ * S_ / BM), 256, 0, stream>>>(
        ob, w_o, out, B_ * S_, H_, H_, mod + 2 * H_, H3_, S_);
}

// Round 2
// 743.071 us; speedup vs baseline: 1.5270x; 1.5270x over previous
//
#include <hip/hip_runtime.h>
#include <hip/hip_bf16.h>
#include <math.h>

// Problem constants
#define B_ 2
#define S_ 2048
#define H_ 1024
#define A_ 1024
#define NH_ 16
#define HD_ 64
#define H3_ 3072
#define EPS_ 1e-5f

typedef __attribute__((ext_vector_type(8))) short short8;   // 8 bf16 in 4 VGPRs
typedef __attribute__((ext_vector_type(4))) float floatx4;  // MFMA accumulator

__device__ inline unsigned short f2bf(float x) {
    union { float f; unsigned u; } v; v.f = x;
    unsigned r = v.u + 0x7fffu + ((v.u >> 16) & 1u);   // RNE
    return (unsigned short)(r >> 16);
}

// ---------------------------------------------------------------------------
// Kernel 1: mod = silu(ada_cond) @ mod_w^T + mod_b     [B, 3H]
// ---------------------------------------------------------------------------
__global__ __launch_bounds__(256) void mod_gemv_kernel(
    const float* __restrict__ ada, const float* __restrict__ mod_w,
    const float* __restrict__ mod_b, float* __restrict__ mod)
{
    int wid = threadIdx.x >> 6;
    int lane = threadIdx.x & 63;
    int idx = blockIdx.x * 4 + wid;       // 0 .. B*3H-1
    int b = idx / H3_;
    int j = idx % H3_;
    const float* ar = ada + (size_t)b * A_;
    const float* wr = mod_w + (size_t)j * A_;
    float acc = 0.f;
    for (int a = lane; a < A_; a += 64) {
        float av = ar[a];
        float sv = av / (1.f + __expf(-av));   // silu
        acc += sv * wr[a];
    }
    #pragma unroll
    for (int m = 1; m < 64; m <<= 1) acc += __shfl_xor(acc, m);
    if (lane == 0) mod[idx] = acc + mod_b[j];
}

// ---------------------------------------------------------------------------
// Kernel 2: h = layernorm(x)*ln_w * (scale+1) + shift   [B,S,H], one block/row
// ---------------------------------------------------------------------------
__global__ __launch_bounds__(256) void ln_mod_kernel(
    const float* __restrict__ x, const float* __restrict__ ln_w,
    const float* __restrict__ mod, float* __restrict__ hout)
{
    int row = blockIdx.x;          // over B*S
    int b = row >> 11;             // row / 2048
    const float* xr = x + (size_t)row * H_;
    int t = threadIdx.x;
    float4 xv = *(const float4*)(xr + t * 4);
    float s1 = xv.x + xv.y + xv.z + xv.w;
    float s2 = xv.x*xv.x + xv.y*xv.y + xv.z*xv.z + xv.w*xv.w;
    #pragma unroll
    for (int m = 1; m < 64; m <<= 1) { s1 += __shfl_xor(s1, m); s2 += __shfl_xor(s2, m); }
    __shared__ float r1[4], r2[4];
    int wid = t >> 6, lane = t & 63;
    if (lane == 0) { r1[wid] = s1; r2[wid] = s2; }
    __syncthreads();
    s1 = r1[0] + r1[1] + r1[2] + r1[3];
    s2 = r2[0] + r2[1] + r2[2] + r2[3];
    float mean = s1 * (1.f / H_);
    float var  = s2 * (1.f / H_) - mean * mean;
    float rstd = rsqrtf(var + EPS_);
    const float* mrow = mod + (size_t)b * H3_;
    float4 wv = *(const float4*)(ln_w + t * 4);
    float4 sc = *(const float4*)(mrow + t * 4);
    float4 sh = *(const float4*)(mrow + H_ + t * 4);
    float4 hv;
    hv.x = (xv.x - mean) * rstd * wv.x * (sc.x + 1.f) + sh.x;
    hv.y = (xv.y - mean) * rstd * wv.y * (sc.y + 1.f) + sh.y;
    hv.z = (xv.z - mean) * rstd * wv.z * (sc.z + 1.f) + sh.z;
    hv.w = (xv.w - mean) * rstd * wv.w * (sc.w + 1.f) + sh.w;
    *(float4*)(hout + (size_t)row * H_ + t * 4) = hv;
}

// ---------------------------------------------------------------------------
// Kernel 3/6: C[M,N] = A[M,K] @ B[N,K]^T  (both K-contiguous), fp32 tiled.
// ---------------------------------------------------------------------------
#define BM 64
#define BN 64
#define BK 16
__global__ __launch_bounds__(256) void gemm_nt_kernel(
    const float* __restrict__ A, const float* __restrict__ Bm,
    float* __restrict__ C, int M, int N, int K,
    const float* __restrict__ gate, int gate_stride, int rows_per_batch)
{
    __shared__ float As[BK][BM + 4];
    __shared__ float Bs[BK][BN + 4];
    int t = threadIdx.x;
    int tx = t & 15, ty = t >> 4;
    int m0 = blockIdx.y * BM, n0 = blockIdx.x * BN;
    int lrow = t >> 2;            // 0..63
    int lk4 = (t & 3) * 4;        // 0,4,8,12
    float acc[4][4] = {};
    for (int k0 = 0; k0 < K; k0 += BK) {
        float4 a4 = *(const float4*)(A + (size_t)(m0 + lrow) * K + k0 + lk4);
        float4 b4 = *(const float4*)(Bm + (size_t)(n0 + lrow) * K + k0 + lk4);
        As[lk4 + 0][lrow] = a4.x; As[lk4 + 1][lrow] = a4.y;
        As[lk4 + 2][lrow] = a4.z; As[lk4 + 3][lrow] = a4.w;
        Bs[lk4 + 0][lrow] = b4.x; Bs[lk4 + 1][lrow] = b4.y;
        Bs[lk4 + 2][lrow] = b4.z; Bs[lk4 + 3][lrow] = b4.w;
        __syncthreads();
        #pragma unroll
        for (int k = 0; k < BK; ++k) {
            float4 af = *(const float4*)&As[k][ty * 4];
            float4 bf = *(const float4*)&Bs[k][tx * 4];
            float ar[4] = {af.x, af.y, af.z, af.w};
            float br[4] = {bf.x, bf.y, bf.z, bf.w};
            #pragma unroll
            for (int i = 0; i < 4; ++i)
                #pragma unroll
                for (int j = 0; j < 4; ++j)
                    acc[i][j] += ar[i] * br[j];
        }
        __syncthreads();
    }
    #pragma unroll
    for (int i = 0; i < 4; ++i) {
        int m = m0 + ty * 4 + i;
        #pragma unroll
        for (int j = 0; j < 4; ++j) {
            int n = n0 + tx * 4 + j;
            float v = acc[i][j];
            if (gate) v *= gate[(m / rows_per_batch) * gate_stride + n];
            C[(size_t)m * N + n] = v;
        }
    }
}

// ---------------------------------------------------------------------------
// Kernel 4: per-head QK layernorm + RoPE; emit bf16 q,k [bh,S,64] (q pre-scaled
// by 1/8) and bf16 V transposed vt [bh,64,S].
// Block = (bh, 64-s block); wave w handles s_local = w*16 .. w*16+15.
// ---------------------------------------------------------------------------
__global__ __launch_bounds__(256) void qk_ln_rope_kernel(
    const float* __restrict__ qkv, const float* __restrict__ freqs,
    const float* __restrict__ qn_w, const float* __restrict__ kn_w,
    unsigned short* __restrict__ qout, unsigned short* __restrict__ kout,
    unsigned short* __restrict__ vtout)
{
    __shared__ unsigned short vt_lds[64][72];
    int t = threadIdx.x;
    int w = t >> 6, lane = t & 63;
    int bh = blockIdx.x >> 5;          // 32 s-blocks per bh
    int sblk = blockIdx.x & 31;
    int h = bh & (NH_ - 1);
    int b = bh >> 4;

    float qnw = qn_w[lane], knw = kn_w[lane];

    for (int it = 0; it < 16; ++it) {
        int s_local = w * 16 + it;
        int s = sblk * 64 + s_local;
        const float* base = qkv + ((size_t)(b * S_ + s)) * H3_;
        float qv = base[h * HD_ + lane];
        float kv = base[H_ + h * HD_ + lane];
        float vv = base[2 * H_ + h * HD_ + lane];

        // layernorm over 64 lanes
        float qs1 = qv, qs2 = qv * qv, ks1 = kv, ks2 = kv * kv;
        #pragma unroll
        for (int m = 1; m < 64; m <<= 1) {
            qs1 += __shfl_xor(qs1, m); qs2 += __shfl_xor(qs2, m);
            ks1 += __shfl_xor(ks1, m); ks2 += __shfl_xor(ks2, m);
        }
        float qm = qs1 * (1.f / 64), qvar = qs2 * (1.f / 64) - qm * qm;
        float km = ks1 * (1.f / 64), kvar = ks2 * (1.f / 64) - km * km;
        qv = (qv - qm) * rsqrtf(qvar + EPS_) * qnw;
        kv = (kv - km) * rsqrtf(kvar + EPS_) * knw;

        // RoPE: interleaved pairs (2i, 2i+1)
        float f0 = freqs[(size_t)s * 64 + (lane >> 1) * 2 + 0];
        float f1 = freqs[(size_t)s * 64 + (lane >> 1) * 2 + 1];
        float qp = __shfl_xor(qv, 1);
        float kp = __shfl_xor(kv, 1);
        float qr = (lane & 1) ? (qv * f0 + qp * f1) : (qv * f0 - qp * f1);
        float kr = (lane & 1) ? (kv * f0 + kp * f1) : (kv * f0 - kp * f1);

        size_t o = ((size_t)bh * S_ + s) * HD_ + lane;
        qout[o] = f2bf(qr * 0.125f);   // fold 1/sqrt(hd) into q (exact pow2)
        kout[o] = f2bf(kr);
        vt_lds[lane][s_local] = f2bf(vv);
    }
    __syncthreads();
    // store vt tile: rows = d (64), cols = 64 s values, coalesced 16B chunks
    for (int i = t; i < 512; i += 256) {
        int r = i >> 3, c8 = i & 7;
        *(uint4*)(vtout + ((size_t)bh * 64 + r) * S_ + sblk * 64 + c8 * 8) =
            *(const uint4*)&vt_lds[r][c8 * 8];
    }
}

// ---------------------------------------------------------------------------
// Kernel 5: bf16-MFMA flash attention.
// Block = (bh, 64-query tile); 4 waves x 16 query rows; K/V tiles of 64.
// q,k: bf16 [bh,S,64] (q pre-scaled); vt: bf16 [bh,64,S]. Out fp32 [B,S,H].
// ---------------------------------------------------------------------------
__global__ __launch_bounds__(256) void attn_mfma_kernel(
    const unsigned short* __restrict__ q, const unsigned short* __restrict__ k,
    const unsigned short* __restrict__ vt, float* __restrict__ o)
{
    __shared__ unsigned short Ks[64][72];
    __shared__ unsigned short Vs[64][72];     // Vs[d][kk]
    __shared__ unsigned short Ps[4][16][72];  // per-wave P staging

    int t = threadIdx.x;
    int w = t >> 6, lane = t & 63;
    int q16 = lane & 15, quad = lane >> 4;
    int bh = blockIdx.y, b = bh >> 4, h = bh & 15;
    int s0 = blockIdx.x * 64;

    // stage Q tile into Ks, pull fragments to registers (kept whole kernel)
    const unsigned short* qg = q + ((size_t)bh * S_ + s0) * HD_;
    for (int i = t; i < 512; i += 256) {
        int r = i >> 3, c8 = i & 7;
        *(uint4*)&Ks[r][c8 * 8] = *(const uint4*)(qg + r * HD_ + c8 * 8);
    }
    __syncthreads();
    short8 qf0 = *(const short8*)&Ks[16 * w + q16][quad * 8];
    short8 qf1 = *(const short8*)&Ks[16 * w + q16][32 + quad * 8];

    floatx4 acc_o[4];
    float m_i[4], l_i[4];
    #pragma unroll
    for (int i = 0; i < 4; ++i) {
        m_i[i] = -3.0e38f; l_i[i] = 0.f;
        acc_o[i] = (floatx4){0.f, 0.f, 0.f, 0.f};
    }

    const unsigned short* kbase = k + ((size_t)bh * S_) * HD_;
    const unsigned short* vbase = vt + (size_t)bh * 64 * S_;

    for (int kt = 0; kt < S_ / 64; ++kt) {
        __syncthreads();   // protect Ks/Vs (also Q-frag reads on iter 0)
        const unsigned short* kg = kbase + (size_t)kt * 64 * HD_;
        const unsigned short* vg = vbase + kt * 64;
        for (int i = t; i < 512; i += 256) {
            int r = i >> 3, c8 = i & 7;
            *(uint4*)&Ks[r][c8 * 8] = *(const uint4*)(kg + r * HD_ + c8 * 8);
            *(uint4*)&Vs[r][c8 * 8] = *(const uint4*)(vg + (size_t)r * S_ + c8 * 8);
        }
        __syncthreads();

        // scores: S[16q][64kk] per wave, 4 col-tiles x 2 d-steps
        floatx4 sc[4];
        #pragma unroll
        for (int nk = 0; nk < 4; ++nk) sc[nk] = (floatx4){0.f, 0.f, 0.f, 0.f};
        #pragma unroll
        for (int nk = 0; nk < 4; ++nk) {
            short8 kf0 = *(const short8*)&Ks[16 * nk + q16][quad * 8];
            short8 kf1 = *(const short8*)&Ks[16 * nk + q16][32 + quad * 8];
            sc[nk] = __builtin_amdgcn_mfma_f32_16x16x32_bf16(qf0, kf0, sc[nk], 0, 0, 0);
            sc[nk] = __builtin_amdgcn_mfma_f32_16x16x32_bf16(qf1, kf1, sc[nk], 0, 0, 0);
        }

        // online softmax; row r = quad*4+i lives in the 16 lanes of this quad
        #pragma unroll
        for (int i = 0; i < 4; ++i) {
            float mx = fmaxf(fmaxf(sc[0][i], sc[1][i]), fmaxf(sc[2][i], sc[3][i]));
            #pragma unroll
            for (int msk = 1; msk < 16; msk <<= 1) mx = fmaxf(mx, __shfl_xor(mx, msk));
            float mnew = fmaxf(m_i[i], mx);
            float alpha = __expf(m_i[i] - mnew);
            m_i[i] = mnew;
            float p0 = __expf(sc[0][i] - mnew);
            float p1 = __expf(sc[1][i] - mnew);
            float p2 = __expf(sc[2][i] - mnew);
            float p3 = __expf(sc[3][i] - mnew);
            float rs = p0 + p1 + p2 + p3;
            #pragma unroll
            for (int msk = 1; msk < 16; msk <<= 1) rs += __shfl_xor(rs, msk);
            l_i[i] = l_i[i] * alpha + rs;
            #pragma unroll
            for (int nd = 0; nd < 4; ++nd) acc_o[nd][i] *= alpha;
            int prow = quad * 4 + i;
            Ps[w][prow][q16]      = f2bf(p0);
            Ps[w][prow][16 + q16] = f2bf(p1);
            Ps[w][prow][32 + q16] = f2bf(p2);
            Ps[w][prow][48 + q16] = f2bf(p3);
        }

        // O += P @ V   (P via per-wave LDS relayout; V from Vs[d][kk])
        #pragma unroll
        for (int ks = 0; ks < 2; ++ks) {
            short8 pf = *(const short8*)&Ps[w][q16][ks * 32 + quad * 8];
            #pragma unroll
            for (int nd = 0; nd < 4; ++nd) {
                short8 vf = *(const short8*)&Vs[16 * nd + q16][ks * 32 + quad * 8];
                acc_o[nd] = __builtin_amdgcn_mfma_f32_16x16x32_bf16(pf, vf, acc_o[nd], 0, 0, 0);
            }
        }
    }

    // epilogue: normalize, scatter to [B,S,H] fp32
    float* og = o + ((size_t)(b * S_ + s0 + 16 * w + quad * 4)) * H_ + h * HD_ + q16;
    #pragma unroll
    for (int i = 0; i < 4; ++i) {
        float inv = 1.f / l_i[i];
        #pragma unroll
        for (int nd = 0; nd < 4; ++nd)
            og[(size_t)i * H_ + 16 * nd] = acc_o[nd][i] * inv;
    }
}

// ---------------------------------------------------------------------------
extern "C" void kernel_launch(void* const* d_in, const int* in_sizes, int n_in,
                              void* d_out, int out_size, void* d_ws, size_t ws_size,
                              hipStream_t stream)
{
    const float* x     = (const float*)d_in[0];
    const float* ada   = (const float*)d_in[1];
    const float* freqs = (const float*)d_in[2];
    const float* w_qkv = (const float*)d_in[3];
    const float* w_o   = (const float*)d_in[4];
    const float* ln_w  = (const float*)d_in[5];
    const float* mod_w = (const float*)d_in[6];
    const float* mod_b = (const float*)d_in[7];
    const float* qn_w  = (const float*)d_in[8];
    const float* kn_w  = (const float*)d_in[9];
    float* out = (float*)d_out;

    float* ws  = (float*)d_ws;
    float* mod = ws;                              // B*3H          = 6144 f
    float* h   = mod + B_ * H3_;                  // B*S*H         f
    float* qkv = h + (size_t)B_ * S_ * H_;        // B*S*3H        f
    unsigned short* qb = (unsigned short*)(qkv + (size_t)B_ * S_ * H3_);
    unsigned short* kb = qb + (size_t)B_ * NH_ * S_ * HD_;
    unsigned short* vtb = kb + (size_t)B_ * NH_ * S_ * HD_;
    float* ob  = h;                               // reuse h for attention out

    mod_gemv_kernel<<<B_ * H3_ / 4, 256, 0, stream>>>(ada, mod_w, mod_b, mod);
    ln_mod_kernel<<<B_ * S_, 256, 0, stream>>>(x, ln_w, mod, h);
    gemm_nt_kernel<<<dim3(H3_ / BN, B_ * S_ / BM), 256, 0, stream>>>(
        h, w_qkv, qkv, B_ * S_, H3_, H_, nullptr, 0, 1);
    qk_ln_rope_kernel<<<B_ * NH_ * S_ / 64, 256, 0, stream>>>(
        qkv, freqs, qn_w, kn_w, qb, kb, vtb);
    attn_mfma_kernel<<<dim3(S_ / 64, B_ * NH_), 256, 0, stream>>>(qb, kb, vtb, ob);
    gemm_nt_kernel<<<dim3(H_ / BN, B_ * S_ / BM), 256, 0, stream>>>(
        ob, w_o, out, B_ * S_, H_, H_, mod + 2 * H_, H3_, S_);
}

// Round 3
// 326.599 us; speedup vs baseline: 3.4742x; 2.2752x over previous
//
#include <hip/hip_runtime.h>
#include <hip/hip_bf16.h>
#include <math.h>

// Problem constants
#define B_ 2
#define S_ 2048
#define H_ 1024
#define A_ 1024
#define NH_ 16
#define HD_ 64
#define H3_ 3072
#define EPS_ 1e-5f

typedef __attribute__((ext_vector_type(8))) short short8;   // 8 bf16 in 4 VGPRs
typedef __attribute__((ext_vector_type(4))) float floatx4;  // MFMA accumulator

__device__ inline unsigned short f2bf(float x) {
    union { float f; unsigned u; } v; v.f = x;
    unsigned r = v.u + 0x7fffu + ((v.u >> 16) & 1u);   // RNE
    return (unsigned short)(r >> 16);
}

// async global->LDS, 16B per lane; LDS dst must be wave-uniform base + lane*16
__device__ inline void gld_lds16(const void* g, void* l) {
    __builtin_amdgcn_global_load_lds(
        (const __attribute__((address_space(1))) unsigned int*)g,
        (__attribute__((address_space(3))) unsigned int*)l, 16, 0, 0);
}

// ---------------------------------------------------------------------------
// Kernel 0: fp32 -> bf16 cast (weights), 8 elems/thread
// ---------------------------------------------------------------------------
__global__ __launch_bounds__(256) void cast_bf16_kernel(
    const float* __restrict__ in, unsigned short* __restrict__ out, int n)
{
    int i = (blockIdx.x * 256 + threadIdx.x) * 8;
    if (i >= n) return;
    float4 a = *(const float4*)(in + i);
    float4 b = *(const float4*)(in + i + 4);
    uint4 o;
    o.x = f2bf(a.x) | ((unsigned)f2bf(a.y) << 16);
    o.y = f2bf(a.z) | ((unsigned)f2bf(a.w) << 16);
    o.z = f2bf(b.x) | ((unsigned)f2bf(b.y) << 16);
    o.w = f2bf(b.z) | ((unsigned)f2bf(b.w) << 16);
    *(uint4*)(out + i) = o;
}

// ---------------------------------------------------------------------------
// Kernel 1: mod = silu(ada_cond) @ mod_w^T + mod_b     [B, 3H]
// ---------------------------------------------------------------------------
__global__ __launch_bounds__(256) void mod_gemv_kernel(
    const float* __restrict__ ada, const float* __restrict__ mod_w,
    const float* __restrict__ mod_b, float* __restrict__ mod)
{
    int wid = threadIdx.x >> 6;
    int lane = threadIdx.x & 63;
    int idx = blockIdx.x * 4 + wid;       // 0 .. B*3H-1
    int b = idx / H3_;
    int j = idx % H3_;
    const float* ar = ada + (size_t)b * A_;
    const float* wr = mod_w + (size_t)j * A_;
    float acc = 0.f;
    for (int a = lane; a < A_; a += 64) {
        float av = ar[a];
        float sv = av / (1.f + __expf(-av));   // silu
        acc += sv * wr[a];
    }
    #pragma unroll
    for (int m = 1; m < 64; m <<= 1) acc += __shfl_xor(acc, m);
    if (lane == 0) mod[idx] = acc + mod_b[j];
}

// ---------------------------------------------------------------------------
// Kernel 2: h = layernorm(x)*ln_w * (scale+1) + shift -> bf16  [B,S,H]
// ---------------------------------------------------------------------------
__global__ __launch_bounds__(256) void ln_mod_kernel(
    const float* __restrict__ x, const float* __restrict__ ln_w,
    const float* __restrict__ mod, unsigned short* __restrict__ hout)
{
    int row = blockIdx.x;          // over B*S
    int b = row >> 11;             // row / 2048
    const float* xr = x + (size_t)row * H_;
    int t = threadIdx.x;
    float4 xv = *(const float4*)(xr + t * 4);
    float s1 = xv.x + xv.y + xv.z + xv.w;
    float s2 = xv.x*xv.x + xv.y*xv.y + xv.z*xv.z + xv.w*xv.w;
    #pragma unroll
    for (int m = 1; m < 64; m <<= 1) { s1 += __shfl_xor(s1, m); s2 += __shfl_xor(s2, m); }
    __shared__ float r1[4], r2[4];
    int wid = t >> 6, lane = t & 63;
    if (lane == 0) { r1[wid] = s1; r2[wid] = s2; }
    __syncthreads();
    s1 = r1[0] + r1[1] + r1[2] + r1[3];
    s2 = r2[0] + r2[1] + r2[2] + r2[3];
    float mean = s1 * (1.f / H_);
    float var  = s2 * (1.f / H_) - mean * mean;
    float rstd = rsqrtf(var + EPS_);
    const float* mrow = mod + (size_t)b * H3_;
    float4 wv = *(const float4*)(ln_w + t * 4);
    float4 sc = *(const float4*)(mrow + t * 4);
    float4 sh = *(const float4*)(mrow + H_ + t * 4);
    float4 hv;
    hv.x = (xv.x - mean) * rstd * wv.x * (sc.x + 1.f) + sh.x;
    hv.y = (xv.y - mean) * rstd * wv.y * (sc.y + 1.f) + sh.y;
    hv.z = (xv.z - mean) * rstd * wv.z * (sc.z + 1.f) + sh.z;
    hv.w = (xv.w - mean) * rstd * wv.w * (sc.w + 1.f) + sh.w;
    uint2 o;
    o.x = f2bf(hv.x) | ((unsigned)f2bf(hv.y) << 16);
    o.y = f2bf(hv.z) | ((unsigned)f2bf(hv.w) << 16);
    *(uint2*)(hout + (size_t)row * H_ + t * 4) = o;
}

// ---------------------------------------------------------------------------
// Kernel 3/6: bf16 MFMA GEMM  C[M,N] = A[M,K] @ B[N,K]^T  (m97 structure)
// 128x128 tile, BK=32, 4 waves (2x2 of 64x64), global_load_lds staging.
// Optional gate: C *= gate[(m>>batch_shift)*gate_stride + n].
// ---------------------------------------------------------------------------
__global__ __launch_bounds__(256) void gemm_bt_bf16_kernel(
    const unsigned short* __restrict__ A, const unsigned short* __restrict__ Bm,
    float* __restrict__ C, int M, int N, int K,
    const float* __restrict__ gate, int gate_stride, int batch_shift)
{
    __shared__ unsigned short As[128 * 32];
    __shared__ unsigned short Bs[128 * 32];
    int t = threadIdx.x;
    int w = t >> 6, lane = t & 63;
    int q16 = lane & 15, quad = lane >> 4;
    int wm = w >> 1, wn = w & 1;
    int m0 = blockIdx.y * 128, n0 = blockIdx.x * 128;

    // staging: wave w loads tile rows 32w..32w+31 of both A and B
    int srow = (w << 5) + (lane >> 2);
    int soff = (lane & 3) << 3;                       // element offset in row
    const unsigned short* ga = A + (size_t)(m0 + srow) * K + soff;
    const unsigned short* gb = Bm + (size_t)(n0 + srow) * K + soff;
    unsigned short* la0 = As + (w << 5) * 32;
    unsigned short* la1 = la0 + 16 * 32;
    unsigned short* lb0 = Bs + (w << 5) * 32;
    unsigned short* lb1 = lb0 + 16 * 32;

    floatx4 acc[4][4];
    #pragma unroll
    for (int mt = 0; mt < 4; ++mt)
        #pragma unroll
        for (int nt = 0; nt < 4; ++nt)
            acc[mt][nt] = (floatx4){0.f, 0.f, 0.f, 0.f};

    int a_row = wm * 64 + q16;
    int b_row = wn * 64 + q16;

    for (int kt = 0; kt < K; kt += 32) {
        __syncthreads();
        gld_lds16(ga, la0);
        gld_lds16(ga + (size_t)16 * K, la1);
        gld_lds16(gb, lb0);
        gld_lds16(gb + (size_t)16 * K, lb1);
        ga += 32; gb += 32;
        __syncthreads();

        short8 af[4], bf[4];
        #pragma unroll
        for (int mt = 0; mt < 4; ++mt)
            af[mt] = *(const short8*)&As[(a_row + mt * 16) * 32 + quad * 8];
        #pragma unroll
        for (int nt = 0; nt < 4; ++nt)
            bf[nt] = *(const short8*)&Bs[(b_row + nt * 16) * 32 + quad * 8];
        #pragma unroll
        for (int mt = 0; mt < 4; ++mt)
            #pragma unroll
            for (int nt = 0; nt < 4; ++nt)
                acc[mt][nt] = __builtin_amdgcn_mfma_f32_16x16x32_bf16(
                    af[mt], bf[nt], acc[mt][nt], 0, 0, 0);
    }

    // epilogue: row m = m0+wm*64+mt*16+quad*4+i, col n = n0+wn*64+nt*16+q16
    #pragma unroll
    for (int mt = 0; mt < 4; ++mt) {
        #pragma unroll
        for (int i = 0; i < 4; ++i) {
            int m = m0 + wm * 64 + mt * 16 + quad * 4 + i;
            float* crow = C + (size_t)m * N;
            const float* grow = gate ? gate + (size_t)(m >> batch_shift) * gate_stride
                                     : nullptr;
            #pragma unroll
            for (int nt = 0; nt < 4; ++nt) {
                int n = n0 + wn * 64 + nt * 16 + q16;
                float v = acc[mt][nt][i];
                if (gate) v *= grow[n];
                crow[n] = v;
            }
        }
    }
}

// ---------------------------------------------------------------------------
// Kernel 4: per-head QK layernorm + RoPE; emit bf16 q,k [bh,S,64] (q pre-scaled
// by 1/8) and bf16 V transposed vt [bh,64,S].
// ---------------------------------------------------------------------------
__global__ __launch_bounds__(256) void qk_ln_rope_kernel(
    const float* __restrict__ qkv, const float* __restrict__ freqs,
    const float* __restrict__ qn_w, const float* __restrict__ kn_w,
    unsigned short* __restrict__ qout, unsigned short* __restrict__ kout,
    unsigned short* __restrict__ vtout)
{
    __shared__ unsigned short vt_lds[64][72];
    int t = threadIdx.x;
    int w = t >> 6, lane = t & 63;
    int bh = blockIdx.x >> 5;          // 32 s-blocks per bh
    int sblk = blockIdx.x & 31;
    int h = bh & (NH_ - 1);
    int b = bh >> 4;

    float qnw = qn_w[lane], knw = kn_w[lane];

    for (int it = 0; it < 16; ++it) {
        int s_local = w * 16 + it;
        int s = sblk * 64 + s_local;
        const float* base = qkv + ((size_t)(b * S_ + s)) * H3_;
        float qv = base[h * HD_ + lane];
        float kv = base[H_ + h * HD_ + lane];
        float vv = base[2 * H_ + h * HD_ + lane];

        float qs1 = qv, qs2 = qv * qv, ks1 = kv, ks2 = kv * kv;
        #pragma unroll
        for (int m = 1; m < 64; m <<= 1) {
            qs1 += __shfl_xor(qs1, m); qs2 += __shfl_xor(qs2, m);
            ks1 += __shfl_xor(ks1, m); ks2 += __shfl_xor(ks2, m);
        }
        float qm = qs1 * (1.f / 64), qvar = qs2 * (1.f / 64) - qm * qm;
        float km = ks1 * (1.f / 64), kvar = ks2 * (1.f / 64) - km * km;
        qv = (qv - qm) * rsqrtf(qvar + EPS_) * qnw;
        kv = (kv - km) * rsqrtf(kvar + EPS_) * knw;

        float f0 = freqs[(size_t)s * 64 + (lane >> 1) * 2 + 0];
        float f1 = freqs[(size_t)s * 64 + (lane >> 1) * 2 + 1];
        float qp = __shfl_xor(qv, 1);
        float kp = __shfl_xor(kv, 1);
        float qr = (lane & 1) ? (qv * f0 + qp * f1) : (qv * f0 - qp * f1);
        float kr = (lane & 1) ? (kv * f0 + kp * f1) : (kv * f0 - kp * f1);

        size_t o = ((size_t)bh * S_ + s) * HD_ + lane;
        qout[o] = f2bf(qr * 0.125f);   // fold 1/sqrt(hd) into q (exact pow2)
        kout[o] = f2bf(kr);
        vt_lds[lane][s_local] = f2bf(vv);
    }
    __syncthreads();
    for (int i = t; i < 512; i += 256) {
        int r = i >> 3, c8 = i & 7;
        *(uint4*)(vtout + ((size_t)bh * 64 + r) * S_ + sblk * 64 + c8 * 8) =
            *(const uint4*)&vt_lds[r][c8 * 8];
    }
}

// ---------------------------------------------------------------------------
// Kernel 5: bf16-MFMA flash attention. Out bf16 [B,S,H].
// ---------------------------------------------------------------------------
__global__ __launch_bounds__(256) void attn_mfma_kernel(
    const unsigned short* __restrict__ q, const unsigned short* __restrict__ k,
    const unsigned short* __restrict__ vt, unsigned short* __restrict__ o)
{
    __shared__ unsigned short Ks[64][72];
    __shared__ unsigned short Vs[64][72];     // Vs[d][kk]
    __shared__ unsigned short Ps[4][16][72];  // per-wave P staging

    int t = threadIdx.x;
    int w = t >> 6, lane = t & 63;
    int q16 = lane & 15, quad = lane >> 4;
    int bh = blockIdx.y, b = bh >> 4, h = bh & 15;
    int s0 = blockIdx.x * 64;

    const unsigned short* qg = q + ((size_t)bh * S_ + s0) * HD_;
    for (int i = t; i < 512; i += 256) {
        int r = i >> 3, c8 = i & 7;
        *(uint4*)&Ks[r][c8 * 8] = *(const uint4*)(qg + r * HD_ + c8 * 8);
    }
    __syncthreads();
    short8 qf0 = *(const short8*)&Ks[16 * w + q16][quad * 8];
    short8 qf1 = *(const short8*)&Ks[16 * w + q16][32 + quad * 8];

    floatx4 acc_o[4];
    float m_i[4], l_i[4];
    #pragma unroll
    for (int i = 0; i < 4; ++i) {
        m_i[i] = -3.0e38f; l_i[i] = 0.f;
        acc_o[i] = (floatx4){0.f, 0.f, 0.f, 0.f};
    }

    const unsigned short* kbase = k + ((size_t)bh * S_) * HD_;
    const unsigned short* vbase = vt + (size_t)bh * 64 * S_;

    for (int kt = 0; kt < S_ / 64; ++kt) {
        __syncthreads();
        const unsigned short* kg = kbase + (size_t)kt * 64 * HD_;
        const unsigned short* vg = vbase + kt * 64;
        for (int i = t; i < 512; i += 256) {
            int r = i >> 3, c8 = i & 7;
            *(uint4*)&Ks[r][c8 * 8] = *(const uint4*)(kg + r * HD_ + c8 * 8);
            *(uint4*)&Vs[r][c8 * 8] = *(const uint4*)(vg + (size_t)r * S_ + c8 * 8);
        }
        __syncthreads();

        floatx4 sc[4];
        #pragma unroll
        for (int nk = 0; nk < 4; ++nk) sc[nk] = (floatx4){0.f, 0.f, 0.f, 0.f};
        #pragma unroll
        for (int nk = 0; nk < 4; ++nk) {
            short8 kf0 = *(const short8*)&Ks[16 * nk + q16][quad * 8];
            short8 kf1 = *(const short8*)&Ks[16 * nk + q16][32 + quad * 8];
            sc[nk] = __builtin_amdgcn_mfma_f32_16x16x32_bf16(qf0, kf0, sc[nk], 0, 0, 0);
            sc[nk] = __builtin_amdgcn_mfma_f32_16x16x32_bf16(qf1, kf1, sc[nk], 0, 0, 0);
        }

        #pragma unroll
        for (int i = 0; i < 4; ++i) {
            float mx = fmaxf(fmaxf(sc[0][i], sc[1][i]), fmaxf(sc[2][i], sc[3][i]));
            #pragma unroll
            for (int msk = 1; msk < 16; msk <<= 1) mx = fmaxf(mx, __shfl_xor(mx, msk));
            float mnew = fmaxf(m_i[i], mx);
            float alpha = __expf(m_i[i] - mnew);
            m_i[i] = mnew;
            float p0 = __expf(sc[0][i] - mnew);
            float p1 = __expf(sc[1][i] - mnew);
            float p2 = __expf(sc[2][i] - mnew);
            float p3 = __expf(sc[3][i] - mnew);
            float rs = p0 + p1 + p2 + p3;
            #pragma unroll
            for (int msk = 1; msk < 16; msk <<= 1) rs += __shfl_xor(rs, msk);
            l_i[i] = l_i[i] * alpha + rs;
            #pragma unroll
            for (int nd = 0; nd < 4; ++nd) acc_o[nd][i] *= alpha;
            int prow = quad * 4 + i;
            Ps[w][prow][q16]      = f2bf(p0);
            Ps[w][prow][16 + q16] = f2bf(p1);
            Ps[w][prow][32 + q16] = f2bf(p2);
            Ps[w][prow][48 + q16] = f2bf(p3);
        }

        #pragma unroll
        for (int ks = 0; ks < 2; ++ks) {
            short8 pf = *(const short8*)&Ps[w][q16][ks * 32 + quad * 8];
            #pragma unroll
            for (int nd = 0; nd < 4; ++nd) {
                short8 vf = *(const short8*)&Vs[16 * nd + q16][ks * 32 + quad * 8];
                acc_o[nd] = __builtin_amdgcn_mfma_f32_16x16x32_bf16(pf, vf, acc_o[nd], 0, 0, 0);
            }
        }
    }

    // epilogue: normalize, bf16, scatter to [B,S,H]
    unsigned short* og = o + ((size_t)(b * S_ + s0 + 16 * w + quad * 4)) * H_ + h * HD_ + q16;
    #pragma unroll
    for (int i = 0; i < 4; ++i) {
        float inv = 1.f / l_i[i];
        #pragma unroll
        for (int nd = 0; nd < 4; ++nd)
            og[(size_t)i * H_ + 16 * nd] = f2bf(acc_o[nd][i] * inv);
    }
}

// ---------------------------------------------------------------------------
extern "C" void kernel_launch(void* const* d_in, const int* in_sizes, int n_in,
                              void* d_out, int out_size, void* d_ws, size_t ws_size,
                              hipStream_t stream)
{
    const float* x     = (const float*)d_in[0];
    const float* ada   = (const float*)d_in[1];
    const float* freqs = (const float*)d_in[2];
    const float* w_qkv = (const float*)d_in[3];
    const float* w_o   = (const float*)d_in[4];
    const float* ln_w  = (const float*)d_in[5];
    const float* mod_w = (const float*)d_in[6];
    const float* mod_b = (const float*)d_in[7];
    const float* qn_w  = (const float*)d_in[8];
    const float* kn_w  = (const float*)d_in[9];
    float* out = (float*)d_out;

    float* ws  = (float*)d_ws;
    float* mod = ws;                                    // 6144 f (pad to 8192)
    float* qkv = mod + 8192;                            // B*S*3H f
    unsigned short* hb    = (unsigned short*)(qkv + (size_t)B_ * S_ * H3_);
    unsigned short* qb    = hb + (size_t)B_ * S_ * H_;
    unsigned short* kb    = qb + (size_t)B_ * S_ * H_;
    unsigned short* vtb   = kb + (size_t)B_ * S_ * H_;
    unsigned short* ob    = vtb + (size_t)B_ * S_ * H_;
    unsigned short* wqkvb = ob + (size_t)B_ * S_ * H_;
    unsigned short* wob   = wqkvb + (size_t)H3_ * H_;

    cast_bf16_kernel<<<H3_ * H_ / (8 * 256), 256, 0, stream>>>(w_qkv, wqkvb, H3_ * H_);
    cast_bf16_kernel<<<H_ * H_ / (8 * 256), 256, 0, stream>>>(w_o, wob, H_ * H_);
    mod_gemv_kernel<<<B_ * H3_ / 4, 256, 0, stream>>>(ada, mod_w, mod_b, mod);
    ln_mod_kernel<<<B_ * S_, 256, 0, stream>>>(x, ln_w, mod, hb);
    gemm_bt_bf16_kernel<<<dim3(H3_ / 128, B_ * S_ / 128), 256, 0, stream>>>(
        hb, wqkvb, qkv, B_ * S_, H3_, H_, nullptr, 0, 0);
    qk_ln_rope_kernel<<<B_ * NH_ * S_ / 64, 256, 0, stream>>>(
        qkv, freqs, qn_w, kn_w, qb, kb, vtb);
    attn_mfma_kernel<<<dim3(S_ / 64, B_ * NH_), 256, 0, stream>>>(qb, kb, vtb, ob);
    gemm_bt_bf16_kernel<<<dim3(H_ / 128, B_ * S_ / 128), 256, 0, stream>>>(
        ob, wob, out, B_ * S_, H_, H_, mod + 2 * H_, H3_, 11);
}

// Round 6
// 304.549 us; speedup vs baseline: 3.7257x; 1.0724x over previous
//
#include <hip/hip_runtime.h>
#include <hip/hip_bf16.h>
#include <math.h>

// Problem constants
#define B_ 2
#define S_ 2048
#define H_ 1024
#define A_ 1024
#define NH_ 16
#define HD_ 64
#define H3_ 3072
#define EPS_ 1e-5f

typedef __attribute__((ext_vector_type(8))) short short8;   // 8 bf16 in 4 VGPRs
typedef __attribute__((ext_vector_type(4))) float floatx4;  // MFMA accumulator

__device__ inline unsigned short f2bf(float x) {
    union { float f; unsigned u; } v; v.f = x;
    unsigned r = v.u + 0x7fffu + ((v.u >> 16) & 1u);   // RNE
    return (unsigned short)(r >> 16);
}

// async global->LDS, 16B per lane; LDS dst must be wave-uniform base + lane*16
__device__ inline void gld_lds16(const void* g, void* l) {
    __builtin_amdgcn_global_load_lds(
        (const __attribute__((address_space(1))) unsigned int*)g,
        (__attribute__((address_space(3))) unsigned int*)l, 16, 0, 0);
}

// ---------------------------------------------------------------------------
// Kernel 0: fp32 -> bf16 cast (weights), 8 elems/thread
// ---------------------------------------------------------------------------
__global__ __launch_bounds__(256) void cast_bf16_kernel(
    const float* __restrict__ in, unsigned short* __restrict__ out, int n)
{
    int i = (blockIdx.x * 256 + threadIdx.x) * 8;
    if (i >= n) return;
    float4 a = *(const float4*)(in + i);
    float4 b = *(const float4*)(in + i + 4);
    uint4 o;
    o.x = f2bf(a.x) | ((unsigned)f2bf(a.y) << 16);
    o.y = f2bf(a.z) | ((unsigned)f2bf(a.w) << 16);
    o.z = f2bf(b.x) | ((unsigned)f2bf(b.y) << 16);
    o.w = f2bf(b.z) | ((unsigned)f2bf(b.w) << 16);
    *(uint4*)(out + i) = o;
}

// ---------------------------------------------------------------------------
// Kernel 1: mod = silu(ada_cond) @ mod_w^T + mod_b     [B, 3H]
// ---------------------------------------------------------------------------
__global__ __launch_bounds__(256) void mod_gemv_kernel(
    const float* __restrict__ ada, const float* __restrict__ mod_w,
    const float* __restrict__ mod_b, float* __restrict__ mod)
{
    int wid = threadIdx.x >> 6;
    int lane = threadIdx.x & 63;
    int idx = blockIdx.x * 4 + wid;       // 0 .. B*3H-1
    int b = idx / H3_;
    int j = idx % H3_;
    const float* ar = ada + (size_t)b * A_;
    const float* wr = mod_w + (size_t)j * A_;
    float acc = 0.f;
    for (int a = lane; a < A_; a += 64) {
        float av = ar[a];
        float sv = av / (1.f + __expf(-av));   // silu
        acc += sv * wr[a];
    }
    #pragma unroll
    for (int m = 1; m < 64; m <<= 1) acc += __shfl_xor(acc, m);
    if (lane == 0) mod[idx] = acc + mod_b[j];
}

// ---------------------------------------------------------------------------
// Kernel 2: h = layernorm(x)*ln_w * (scale+1) + shift -> bf16  [B,S,H]
// ---------------------------------------------------------------------------
__global__ __launch_bounds__(256) void ln_mod_kernel(
    const float* __restrict__ x, const float* __restrict__ ln_w,
    const float* __restrict__ mod, unsigned short* __restrict__ hout)
{
    int row = blockIdx.x;          // over B*S
    int b = row >> 11;             // row / 2048
    const float* xr = x + (size_t)row * H_;
    int t = threadIdx.x;
    float4 xv = *(const float4*)(xr + t * 4);
    float s1 = xv.x + xv.y + xv.z + xv.w;
    float s2 = xv.x*xv.x + xv.y*xv.y + xv.z*xv.z + xv.w*xv.w;
    #pragma unroll
    for (int m = 1; m < 64; m <<= 1) { s1 += __shfl_xor(s1, m); s2 += __shfl_xor(s2, m); }
    __shared__ float r1[4], r2[4];
    int wid = t >> 6, lane = t & 63;
    if (lane == 0) { r1[wid] = s1; r2[wid] = s2; }
    __syncthreads();
    s1 = r1[0] + r1[1] + r1[2] + r1[3];
    s2 = r2[0] + r2[1] + r2[2] + r2[3];
    float mean = s1 * (1.f / H_);
    float var  = s2 * (1.f / H_) - mean * mean;
    float rstd = rsqrtf(var + EPS_);
    const float* mrow = mod + (size_t)b * H3_;
    float4 wv = *(const float4*)(ln_w + t * 4);
    float4 sc = *(const float4*)(mrow + t * 4);
    float4 sh = *(const float4*)(mrow + H_ + t * 4);
    float4 hv;
    hv.x = (xv.x - mean) * rstd * wv.x * (sc.x + 1.f) + sh.x;
    hv.y = (xv.y - mean) * rstd * wv.y * (sc.y + 1.f) + sh.y;
    hv.z = (xv.z - mean) * rstd * wv.z * (sc.z + 1.f) + sh.z;
    hv.w = (xv.w - mean) * rstd * wv.w * (sc.w + 1.f) + sh.w;
    uint2 o;
    o.x = f2bf(hv.x) | ((unsigned)f2bf(hv.y) << 16);
    o.y = f2bf(hv.z) | ((unsigned)f2bf(hv.w) << 16);
    *(uint2*)(hout + (size_t)row * H_ + t * 4) = o;
}

// ---------------------------------------------------------------------------
// Kernel 3/6: bf16 MFMA GEMM  C[M,N] = A[M,K] @ B[N,K]^T  (m97 structure)
// ---------------------------------------------------------------------------
__global__ __launch_bounds__(256) void gemm_bt_bf16_kernel(
    const unsigned short* __restrict__ A, const unsigned short* __restrict__ Bm,
    float* __restrict__ C, int M, int N, int K,
    const float* __restrict__ gate, int gate_stride, int batch_shift)
{
    __shared__ unsigned short As[128 * 32];
    __shared__ unsigned short Bs[128 * 32];
    int t = threadIdx.x;
    int w = t >> 6, lane = t & 63;
    int q16 = lane & 15, quad = lane >> 4;
    int wm = w >> 1, wn = w & 1;
    int m0 = blockIdx.y * 128, n0 = blockIdx.x * 128;

    int srow = (w << 5) + (lane >> 2);
    int soff = (lane & 3) << 3;                       // element offset in row
    const unsigned short* ga = A + (size_t)(m0 + srow) * K + soff;
    const unsigned short* gb = Bm + (size_t)(n0 + srow) * K + soff;
    unsigned short* la0 = As + (w << 5) * 32;
    unsigned short* la1 = la0 + 16 * 32;
    unsigned short* lb0 = Bs + (w << 5) * 32;
    unsigned short* lb1 = lb0 + 16 * 32;

    floatx4 acc[4][4];
    #pragma unroll
    for (int mt = 0; mt < 4; ++mt)
        #pragma unroll
        for (int nt = 0; nt < 4; ++nt)
            acc[mt][nt] = (floatx4){0.f, 0.f, 0.f, 0.f};

    int a_row = wm * 64 + q16;
    int b_row = wn * 64 + q16;

    for (int kt = 0; kt < K; kt += 32) {
        __syncthreads();
        gld_lds16(ga, la0);
        gld_lds16(ga + (size_t)16 * K, la1);
        gld_lds16(gb, lb0);
        gld_lds16(gb + (size_t)16 * K, lb1);
        ga += 32; gb += 32;
        __syncthreads();

        short8 af[4], bf[4];
        #pragma unroll
        for (int mt = 0; mt < 4; ++mt)
            af[mt] = *(const short8*)&As[(a_row + mt * 16) * 32 + quad * 8];
        #pragma unroll
        for (int nt = 0; nt < 4; ++nt)
            bf[nt] = *(const short8*)&Bs[(b_row + nt * 16) * 32 + quad * 8];
        #pragma unroll
        for (int mt = 0; mt < 4; ++mt)
            #pragma unroll
            for (int nt = 0; nt < 4; ++nt)
                acc[mt][nt] = __builtin_amdgcn_mfma_f32_16x16x32_bf16(
                    af[mt], bf[nt], acc[mt][nt], 0, 0, 0);
    }

    #pragma unroll
    for (int mt = 0; mt < 4; ++mt) {
        #pragma unroll
        for (int i = 0; i < 4; ++i) {
            int m = m0 + wm * 64 + mt * 16 + quad * 4 + i;
            float* crow = C + (size_t)m * N;
            const float* grow = gate ? gate + (size_t)(m >> batch_shift) * gate_stride
                                     : nullptr;
            #pragma unroll
            for (int nt = 0; nt < 4; ++nt) {
                int n = n0 + wn * 64 + nt * 16 + q16;
                float v = acc[mt][nt][i];
                if (gate) v *= grow[n];
                crow[n] = v;
            }
        }
    }
}

// ---------------------------------------------------------------------------
// Kernel 4: per-head QK layernorm + RoPE; emit bf16 q,k [bh,S,64]
// (q pre-scaled by log2(e)/8 for exp2-domain softmax) and vt [bh,64,S].
// ---------------------------------------------------------------------------
__global__ __launch_bounds__(256) void qk_ln_rope_kernel(
    const float* __restrict__ qkv, const float* __restrict__ freqs,
    const float* __restrict__ qn_w, const float* __restrict__ kn_w,
    unsigned short* __restrict__ qout, unsigned short* __restrict__ kout,
    unsigned short* __restrict__ vtout)
{
    __shared__ unsigned short vt_lds[64][72];
    int t = threadIdx.x;
    int w = t >> 6, lane = t & 63;
    int bh = blockIdx.x >> 5;          // 32 s-blocks per bh
    int sblk = blockIdx.x & 31;
    int h = bh & (NH_ - 1);
    int b = bh >> 4;

    float qnw = qn_w[lane], knw = kn_w[lane];

    for (int it = 0; it < 16; ++it) {
        int s_local = w * 16 + it;
        int s = sblk * 64 + s_local;
        const float* base = qkv + ((size_t)(b * S_ + s)) * H3_;
        float qv = base[h * HD_ + lane];
        float kv = base[H_ + h * HD_ + lane];
        float vv = base[2 * H_ + h * HD_ + lane];

        float qs1 = qv, qs2 = qv * qv, ks1 = kv, ks2 = kv * kv;
        #pragma unroll
        for (int m = 1; m < 64; m <<= 1) {
            qs1 += __shfl_xor(qs1, m); qs2 += __shfl_xor(qs2, m);
            ks1 += __shfl_xor(ks1, m); ks2 += __shfl_xor(ks2, m);
        }
        float qm = qs1 * (1.f / 64), qvar = qs2 * (1.f / 64) - qm * qm;
        float km = ks1 * (1.f / 64), kvar = ks2 * (1.f / 64) - km * km;
        qv = (qv - qm) * rsqrtf(qvar + EPS_) * qnw;
        kv = (kv - km) * rsqrtf(kvar + EPS_) * knw;

        float f0 = freqs[(size_t)s * 64 + (lane >> 1) * 2 + 0];
        float f1 = freqs[(size_t)s * 64 + (lane >> 1) * 2 + 1];
        float qp = __shfl_xor(qv, 1);
        float kp = __shfl_xor(kv, 1);
        float qr = (lane & 1) ? (qv * f0 + qp * f1) : (qv * f0 - qp * f1);
        float kr = (lane & 1) ? (kv * f0 + kp * f1) : (kv * f0 - kp * f1);

        size_t o = ((size_t)bh * S_ + s) * HD_ + lane;
        qout[o] = f2bf(qr * 0.1803368801111244f);  // (1/8)*log2(e)
        kout[o] = f2bf(kr);
        vt_lds[lane][s_local] = f2bf(vv);
    }
    __syncthreads();
    for (int i = t; i < 512; i += 256) {
        int r = i >> 3, c8 = i & 7;
        *(uint4*)(vtout + ((size_t)bh * 64 + r) * S_ + sblk * 64 + c8 * 8) =
            *(const uint4*)&vt_lds[r][c8 * 8];
    }
}

// ---------------------------------------------------------------------------
// Kernel 5: bf16-MFMA flash attention, transposed-S/O formulation.
// S^T = K.Q^T (C-layout: col=query) -> per-lane softmax state for ONE query.
// O^T = V^T.P accumulated in C-layout (col=query) -> per-lane alpha rescale.
// Epilogue: transpose O^T->O via per-wave LDS tile; 8 chunks of 8 bf16 per
// query row, quad q owns chunks {2q, 2q+1} (round-4/5 bug: c=4i+quad gave
// 16 chunks -> OOB reads + cross-head output clobber -> NaN).
// ---------------------------------------------------------------------------
__global__ __launch_bounds__(256) void attn_mfma_kernel(
    const unsigned short* __restrict__ q, const unsigned short* __restrict__ k,
    const unsigned short* __restrict__ vt, unsigned short* __restrict__ o)
{
    __shared__ unsigned short Ks[64][72];
    __shared__ unsigned short Vs[64][72];     // Vs[d][kk]
    __shared__ unsigned short Ps[4][16][72];  // per-wave staging [query][key or d]

    int t = threadIdx.x;
    int w = t >> 6, lane = t & 63;
    int q16 = lane & 15, quad = lane >> 4;
    int bh = blockIdx.y, b = bh >> 4, h = bh & 15;
    int s0 = blockIdx.x * 64;

    const unsigned short* qg = q + ((size_t)bh * S_ + s0) * HD_;
    for (int i = t; i < 512; i += 256) {
        int r = i >> 3, c8 = i & 7;
        *(uint4*)&Ks[r][c8 * 8] = *(const uint4*)(qg + r * HD_ + c8 * 8);
    }
    __syncthreads();
    short8 qf0 = *(const short8*)&Ks[16 * w + q16][quad * 8];
    short8 qf1 = *(const short8*)&Ks[16 * w + q16][32 + quad * 8];

    // O^T accumulator: acc_o[nd][i] = O^T[d=16*nd+quad*4+i][query=16w+q16]
    floatx4 acc_o[4];
    float m_i = -3.0e38f, l_i = 0.f;    // per-lane: query 16w+q16
    #pragma unroll
    for (int i = 0; i < 4; ++i) acc_o[i] = (floatx4){0.f, 0.f, 0.f, 0.f};

    const unsigned short* kbase = k + ((size_t)bh * S_) * HD_;
    const unsigned short* vbase = vt + (size_t)bh * 64 * S_;

    for (int kt = 0; kt < S_ / 64; ++kt) {
        __syncthreads();
        const unsigned short* kg = kbase + (size_t)kt * 64 * HD_;
        const unsigned short* vg = vbase + kt * 64;
        for (int i = t; i < 512; i += 256) {
            int r = i >> 3, c8 = i & 7;
            *(uint4*)&Ks[r][c8 * 8] = *(const uint4*)(kg + r * HD_ + c8 * 8);
            *(uint4*)&Vs[r][c8 * 8] = *(const uint4*)(vg + (size_t)r * S_ + c8 * 8);
        }
        __syncthreads();

        // S^T tiles: sc[nk][i] = S^T[key=16nk+quad*4+i][query=16w+q16]
        floatx4 sc[4];
        #pragma unroll
        for (int nk = 0; nk < 4; ++nk) sc[nk] = (floatx4){0.f, 0.f, 0.f, 0.f};
        #pragma unroll
        for (int nk = 0; nk < 4; ++nk) {
            short8 kf0 = *(const short8*)&Ks[16 * nk + q16][quad * 8];
            short8 kf1 = *(const short8*)&Ks[16 * nk + q16][32 + quad * 8];
            sc[nk] = __builtin_amdgcn_mfma_f32_16x16x32_bf16(kf0, qf0, sc[nk], 0, 0, 0);
            sc[nk] = __builtin_amdgcn_mfma_f32_16x16x32_bf16(kf1, qf1, sc[nk], 0, 0, 0);
        }

        // max over this lane's 16 keys, then across quads (xor 16, 32)
        float mx0 = fmaxf(fmaxf(sc[0][0], sc[0][1]), fmaxf(sc[0][2], sc[0][3]));
        float mx1 = fmaxf(fmaxf(sc[1][0], sc[1][1]), fmaxf(sc[1][2], sc[1][3]));
        float mx2 = fmaxf(fmaxf(sc[2][0], sc[2][1]), fmaxf(sc[2][2], sc[2][3]));
        float mx3 = fmaxf(fmaxf(sc[3][0], sc[3][1]), fmaxf(sc[3][2], sc[3][3]));
        float mx = fmaxf(fmaxf(mx0, mx1), fmaxf(mx2, mx3));
        mx = fmaxf(mx, __shfl_xor(mx, 16));
        mx = fmaxf(mx, __shfl_xor(mx, 32));
        float mnew = fmaxf(m_i, mx);
        float alpha = exp2f(m_i - mnew);
        m_i = mnew;

        // p = exp2(s - m); 4 consecutive keys per nk (declared-type stores)
        float rs = 0.f;
        #pragma unroll
        for (int nk = 0; nk < 4; ++nk) {
            float p0 = exp2f(sc[nk][0] - mnew);
            float p1 = exp2f(sc[nk][1] - mnew);
            float p2 = exp2f(sc[nk][2] - mnew);
            float p3 = exp2f(sc[nk][3] - mnew);
            rs += (p0 + p1) + (p2 + p3);
            unsigned short* pp = &Ps[w][q16][16 * nk + quad * 4];
            pp[0] = f2bf(p0); pp[1] = f2bf(p1);
            pp[2] = f2bf(p2); pp[3] = f2bf(p3);
        }
        rs += __shfl_xor(rs, 16);
        rs += __shfl_xor(rs, 32);
        l_i = l_i * alpha + rs;

        #pragma unroll
        for (int nd = 0; nd < 4; ++nd) {
            acc_o[nd][0] *= alpha; acc_o[nd][1] *= alpha;
            acc_o[nd][2] *= alpha; acc_o[nd][3] *= alpha;
        }

        // fence: P writes must not be reordered vs the P fragment reads below
        __asm__ __volatile__("" ::: "memory");

        // O^T += V^T @ P   (A: Vs[d][key], B: Ps[query][key])
        #pragma unroll
        for (int ks = 0; ks < 2; ++ks) {
            short8 pf = *(const short8*)&Ps[w][q16][ks * 32 + quad * 8];
            #pragma unroll
            for (int nd = 0; nd < 4; ++nd) {
                short8 vf = *(const short8*)&Vs[16 * nd + q16][ks * 32 + quad * 8];
                acc_o[nd] = __builtin_amdgcn_mfma_f32_16x16x32_bf16(vf, pf, acc_o[nd], 0, 0, 0);
            }
        }
    }

    // epilogue: normalize by own l, transpose O^T->O via per-wave LDS tile
    float inv = 1.f / l_i;
    #pragma unroll
    for (int nd = 0; nd < 4; ++nd) {
        unsigned short* pp = &Ps[w][q16][16 * nd + quad * 4];
        pp[0] = f2bf(acc_o[nd][0] * inv);
        pp[1] = f2bf(acc_o[nd][1] * inv);
        pp[2] = f2bf(acc_o[nd][2] * inv);
        pp[3] = f2bf(acc_o[nd][3] * inv);
    }
    __asm__ __volatile__("" ::: "memory");
    // store: row = query 16w+q16; 8 chunks of 8 bf16; quad owns chunks 2q,2q+1
    unsigned short* og = o + ((size_t)(b * S_ + s0 + 16 * w + q16)) * H_ + h * HD_;
    #pragma unroll
    for (int i = 0; i < 2; ++i) {
        int c = quad * 2 + i;          // 0..7
        *(short8*)(og + c * 8) = *(const short8*)&Ps[w][q16][c * 8];
    }
}

// ---------------------------------------------------------------------------
extern "C" void kernel_launch(void* const* d_in, const int* in_sizes, int n_in,
                              void* d_out, int out_size, void* d_ws, size_t ws_size,
                              hipStream_t stream)
{
    const float* x     = (const float*)d_in[0];
    const float* ada   = (const float*)d_in[1];
    const float* freqs = (const float*)d_in[2];
    const float* w_qkv = (const float*)d_in[3];
    const float* w_o   = (const float*)d_in[4];
    const float* ln_w  = (const float*)d_in[5];
    const float* mod_w = (const float*)d_in[6];
    const float* mod_b = (const float*)d_in[7];
    const float* qn_w  = (const float*)d_in[8];
    const float* kn_w  = (const float*)d_in[9];
    float* out = (float*)d_out;

    float* ws  = (float*)d_ws;
    float* mod = ws;                                    // 6144 f (pad to 8192)
    float* qkv = mod + 8192;                            // B*S*3H f
    unsigned short* hb    = (unsigned short*)(qkv + (size_t)B_ * S_ * H3_);
    unsigned short* qb    = hb + (size_t)B_ * S_ * H_;
    unsigned short* kb    = qb + (size_t)B_ * S_ * H_;
    unsigned short* vtb   = kb + (size_t)B_ * S_ * H_;
    unsigned short* ob    = vtb + (size_t)B_ * S_ * H_;
    unsigned short* wqkvb = ob + (size_t)B_ * S_ * H_;
    unsigned short* wob   = wqkvb + (size_t)H3_ * H_;

    cast_bf16_kernel<<<H3_ * H_ / (8 * 256), 256, 0, stream>>>(w_qkv, wqkvb, H3_ * H_);
    cast_bf16_kernel<<<H_ * H_ / (8 * 256), 256, 0, stream>>>(w_o, wob, H_ * H_);
    mod_gemv_kernel<<<B_ * H3_ / 4, 256, 0, stream>>>(ada, mod_w, mod_b, mod);
    ln_mod_kernel<<<B_ * S_, 256, 0, stream>>>(x, ln_w, mod, hb);
    gemm_bt_bf16_kernel<<<dim3(H3_ / 128, B_ * S_ / 128), 256, 0, stream>>>(
        hb, wqkvb, qkv, B_ * S_, H3_, H_, nullptr, 0, 0);
    qk_ln_rope_kernel<<<B_ * NH_ * S_ / 64, 256, 0, stream>>>(
        qkv, freqs, qn_w, kn_w, qb, kb, vtb);
    attn_mfma_kernel<<<dim3(S_ / 64, B_ * NH_), 256, 0, stream>>>(qb, kb, vtb, ob);
    gemm_bt_bf16_kernel<<<dim3(H_ / 128, B_ * S_ / 128), 256, 0, stream>>>(
        ob, wob, out, B_ * S_, H_, H_, mod + 2 * H_, H3_, 11);
}

// Round 7
// 301.877 us; speedup vs baseline: 3.7587x; 1.0089x over previous
//
#include <hip/hip_runtime.h>
#include <hip/hip_bf16.h>
#include <math.h>

// Problem constants
#define B_ 2
#define S_ 2048
#define H_ 1024
#define A_ 1024
#define NH_ 16
#define HD_ 64
#define H3_ 3072
#define EPS_ 1e-5f

typedef __attribute__((ext_vector_type(8))) short short8;   // 8 bf16 in 4 VGPRs
typedef __attribute__((ext_vector_type(4))) float floatx4;  // MFMA accumulator

__device__ inline unsigned short f2bf(float x) {
    union { float f; unsigned u; } v; v.f = x;
    unsigned r = v.u + 0x7fffu + ((v.u >> 16) & 1u);   // RNE
    return (unsigned short)(r >> 16);
}

// packed f32x2 -> bf16x2 (v_cvt_pk_bf16_f32 on gfx950)
__device__ inline unsigned pk_bf16(float a, float b) {
    union { __hip_bfloat162 h; unsigned u; } v;
    v.h = __float22bfloat162_rn(make_float2(a, b));
    return v.u;
}

// async global->LDS, 16B per lane; LDS dst must be wave-uniform base + lane*16
__device__ inline void gld_lds16(const void* g, void* l) {
    __builtin_amdgcn_global_load_lds(
        (const __attribute__((address_space(1))) unsigned int*)g,
        (__attribute__((address_space(3))) unsigned int*)l, 16, 0, 0);
}

// block-padded attention tile layout: 8-row blocks (1024 B) + 64 B pad each.
// row r (0..63), 64 ushorts/row: offset = (r>>3)*544 + (r&7)*64   [ushorts]
#define TBLK(r) ((((r) >> 3) * 544) + (((r) & 7) * 64))

// ---------------------------------------------------------------------------
// Kernel 0: fp32 -> bf16 cast (weights), 8 elems/thread
// ---------------------------------------------------------------------------
__global__ __launch_bounds__(256) void cast_bf16_kernel(
    const float* __restrict__ in, unsigned short* __restrict__ out, int n)
{
    int i = (blockIdx.x * 256 + threadIdx.x) * 8;
    if (i >= n) return;
    float4 a = *(const float4*)(in + i);
    float4 b = *(const float4*)(in + i + 4);
    uint4 o;
    o.x = pk_bf16(a.x, a.y);
    o.y = pk_bf16(a.z, a.w);
    o.z = pk_bf16(b.x, b.y);
    o.w = pk_bf16(b.z, b.w);
    *(uint4*)(out + i) = o;
}

// ---------------------------------------------------------------------------
// Kernel 1: mod = silu(ada_cond) @ mod_w^T + mod_b     [B, 3H]
// ---------------------------------------------------------------------------
__global__ __launch_bounds__(256) void mod_gemv_kernel(
    const float* __restrict__ ada, const float* __restrict__ mod_w,
    const float* __restrict__ mod_b, float* __restrict__ mod)
{
    int wid = threadIdx.x >> 6;
    int lane = threadIdx.x & 63;
    int idx = blockIdx.x * 4 + wid;       // 0 .. B*3H-1
    int b = idx / H3_;
    int j = idx % H3_;
    const float* ar = ada + (size_t)b * A_;
    const float* wr = mod_w + (size_t)j * A_;
    float acc = 0.f;
    for (int a = lane; a < A_; a += 64) {
        float av = ar[a];
        float sv = av / (1.f + __expf(-av));   // silu
        acc += sv * wr[a];
    }
    #pragma unroll
    for (int m = 1; m < 64; m <<= 1) acc += __shfl_xor(acc, m);
    if (lane == 0) mod[idx] = acc + mod_b[j];
}

// ---------------------------------------------------------------------------
// Kernel 2: h = layernorm(x)*ln_w * (scale+1) + shift -> bf16  [B,S,H]
// ---------------------------------------------------------------------------
__global__ __launch_bounds__(256) void ln_mod_kernel(
    const float* __restrict__ x, const float* __restrict__ ln_w,
    const float* __restrict__ mod, unsigned short* __restrict__ hout)
{
    int row = blockIdx.x;          // over B*S
    int b = row >> 11;             // row / 2048
    const float* xr = x + (size_t)row * H_;
    int t = threadIdx.x;
    float4 xv = *(const float4*)(xr + t * 4);
    float s1 = xv.x + xv.y + xv.z + xv.w;
    float s2 = xv.x*xv.x + xv.y*xv.y + xv.z*xv.z + xv.w*xv.w;
    #pragma unroll
    for (int m = 1; m < 64; m <<= 1) { s1 += __shfl_xor(s1, m); s2 += __shfl_xor(s2, m); }
    __shared__ float r1[4], r2[4];
    int wid = t >> 6, lane = t & 63;
    if (lane == 0) { r1[wid] = s1; r2[wid] = s2; }
    __syncthreads();
    s1 = r1[0] + r1[1] + r1[2] + r1[3];
    s2 = r2[0] + r2[1] + r2[2] + r2[3];
    float mean = s1 * (1.f / H_);
    float var  = s2 * (1.f / H_) - mean * mean;
    float rstd = rsqrtf(var + EPS_);
    const float* mrow = mod + (size_t)b * H3_;
    float4 wv = *(const float4*)(ln_w + t * 4);
    float4 sc = *(const float4*)(mrow + t * 4);
    float4 sh = *(const float4*)(mrow + H_ + t * 4);
    float4 hv;
    hv.x = (xv.x - mean) * rstd * wv.x * (sc.x + 1.f) + sh.x;
    hv.y = (xv.y - mean) * rstd * wv.y * (sc.y + 1.f) + sh.y;
    hv.z = (xv.z - mean) * rstd * wv.z * (sc.z + 1.f) + sh.z;
    hv.w = (xv.w - mean) * rstd * wv.w * (sc.w + 1.f) + sh.w;
    uint2 o;
    o.x = pk_bf16(hv.x, hv.y);
    o.y = pk_bf16(hv.z, hv.w);
    *(uint2*)(hout + (size_t)row * H_ + t * 4) = o;
}

// ---------------------------------------------------------------------------
// Kernel 3/6: bf16 MFMA GEMM  C[M,N] = A[M,K] @ B[N,K]^T  (m97 structure)
// ---------------------------------------------------------------------------
__global__ __launch_bounds__(256) void gemm_bt_bf16_kernel(
    const unsigned short* __restrict__ A, const unsigned short* __restrict__ Bm,
    float* __restrict__ C, int M, int N, int K,
    const float* __restrict__ gate, int gate_stride, int batch_shift)
{
    __shared__ unsigned short As[128 * 32];
    __shared__ unsigned short Bs[128 * 32];
    int t = threadIdx.x;
    int w = t >> 6, lane = t & 63;
    int q16 = lane & 15, quad = lane >> 4;
    int wm = w >> 1, wn = w & 1;
    int m0 = blockIdx.y * 128, n0 = blockIdx.x * 128;

    int srow = (w << 5) + (lane >> 2);
    int soff = (lane & 3) << 3;                       // element offset in row
    const unsigned short* ga = A + (size_t)(m0 + srow) * K + soff;
    const unsigned short* gb = Bm + (size_t)(n0 + srow) * K + soff;
    unsigned short* la0 = As + (w << 5) * 32;
    unsigned short* la1 = la0 + 16 * 32;
    unsigned short* lb0 = Bs + (w << 5) * 32;
    unsigned short* lb1 = lb0 + 16 * 32;

    floatx4 acc[4][4];
    #pragma unroll
    for (int mt = 0; mt < 4; ++mt)
        #pragma unroll
        for (int nt = 0; nt < 4; ++nt)
            acc[mt][nt] = (floatx4){0.f, 0.f, 0.f, 0.f};

    int a_row = wm * 64 + q16;
    int b_row = wn * 64 + q16;

    for (int kt = 0; kt < K; kt += 32) {
        __syncthreads();
        gld_lds16(ga, la0);
        gld_lds16(ga + (size_t)16 * K, la1);
        gld_lds16(gb, lb0);
        gld_lds16(gb + (size_t)16 * K, lb1);
        ga += 32; gb += 32;
        __syncthreads();

        short8 af[4], bf[4];
        #pragma unroll
        for (int mt = 0; mt < 4; ++mt)
            af[mt] = *(const short8*)&As[(a_row + mt * 16) * 32 + quad * 8];
        #pragma unroll
        for (int nt = 0; nt < 4; ++nt)
            bf[nt] = *(const short8*)&Bs[(b_row + nt * 16) * 32 + quad * 8];
        #pragma unroll
        for (int mt = 0; mt < 4; ++mt)
            #pragma unroll
            for (int nt = 0; nt < 4; ++nt)
                acc[mt][nt] = __builtin_amdgcn_mfma_f32_16x16x32_bf16(
                    af[mt], bf[nt], acc[mt][nt], 0, 0, 0);
    }

    #pragma unroll
    for (int mt = 0; mt < 4; ++mt) {
        #pragma unroll
        for (int i = 0; i < 4; ++i) {
            int m = m0 + wm * 64 + mt * 16 + quad * 4 + i;
            float* crow = C + (size_t)m * N;
            const float* grow = gate ? gate + (size_t)(m >> batch_shift) * gate_stride
                                     : nullptr;
            #pragma unroll
            for (int nt = 0; nt < 4; ++nt) {
                int n = n0 + wn * 64 + nt * 16 + q16;
                float v = acc[mt][nt][i];
                if (gate) v *= grow[n];
                crow[n] = v;
            }
        }
    }
}

// ---------------------------------------------------------------------------
// Kernel 4: per-head QK layernorm + RoPE; emit bf16 q,k [bh,S,64]
// (q pre-scaled by log2(e)/8 for exp2-domain softmax) and vt [bh,64,S].
// ---------------------------------------------------------------------------
__global__ __launch_bounds__(256) void qk_ln_rope_kernel(
    const float* __restrict__ qkv, const float* __restrict__ freqs,
    const float* __restrict__ qn_w, const float* __restrict__ kn_w,
    unsigned short* __restrict__ qout, unsigned short* __restrict__ kout,
    unsigned short* __restrict__ vtout)
{
    __shared__ unsigned short vt_lds[64][72];
    int t = threadIdx.x;
    int w = t >> 6, lane = t & 63;
    int bh = blockIdx.x >> 5;          // 32 s-blocks per bh
    int sblk = blockIdx.x & 31;
    int h = bh & (NH_ - 1);
    int b = bh >> 4;

    float qnw = qn_w[lane], knw = kn_w[lane];

    for (int it = 0; it < 16; ++it) {
        int s_local = w * 16 + it;
        int s = sblk * 64 + s_local;
        const float* base = qkv + ((size_t)(b * S_ + s)) * H3_;
        float qv = base[h * HD_ + lane];
        float kv = base[H_ + h * HD_ + lane];
        float vv = base[2 * H_ + h * HD_ + lane];

        float qs1 = qv, qs2 = qv * qv, ks1 = kv, ks2 = kv * kv;
        #pragma unroll
        for (int m = 1; m < 64; m <<= 1) {
            qs1 += __shfl_xor(qs1, m); qs2 += __shfl_xor(qs2, m);
            ks1 += __shfl_xor(ks1, m); ks2 += __shfl_xor(ks2, m);
        }
        float qm = qs1 * (1.f / 64), qvar = qs2 * (1.f / 64) - qm * qm;
        float km = ks1 * (1.f / 64), kvar = ks2 * (1.f / 64) - km * km;
        qv = (qv - qm) * rsqrtf(qvar + EPS_) * qnw;
        kv = (kv - km) * rsqrtf(kvar + EPS_) * knw;

        float f0 = freqs[(size_t)s * 64 + (lane >> 1) * 2 + 0];
        float f1 = freqs[(size_t)s * 64 + (lane >> 1) * 2 + 1];
        float qp = __shfl_xor(qv, 1);
        float kp = __shfl_xor(kv, 1);
        float qr = (lane & 1) ? (qv * f0 + qp * f1) : (qv * f0 - qp * f1);
        float kr = (lane & 1) ? (kv * f0 + kp * f1) : (kv * f0 - kp * f1);

        size_t o = ((size_t)bh * S_ + s) * HD_ + lane;
        qout[o] = f2bf(qr * 0.1803368801111244f);  // (1/8)*log2(e)
        kout[o] = f2bf(kr);
        vt_lds[lane][s_local] = f2bf(vv);
    }
    __syncthreads();
    for (int i = t; i < 512; i += 256) {
        int r = i >> 3, c8 = i & 7;
        *(uint4*)(vtout + ((size_t)bh * 64 + r) * S_ + sblk * 64 + c8 * 8) =
            *(const uint4*)&vt_lds[r][c8 * 8];
    }
}

// ---------------------------------------------------------------------------
// Kernel 5: bf16-MFMA flash attention, transposed-S/O formulation.
// Q/K/V staged via global_load_lds into block-padded tiles (conflict-free
// b128 fragment reads). Per-lane softmax state (one query per lane).
// ---------------------------------------------------------------------------
__global__ __launch_bounds__(256) void attn_mfma_kernel(
    const unsigned short* __restrict__ q, const unsigned short* __restrict__ k,
    const unsigned short* __restrict__ vt, unsigned short* __restrict__ o)
{
    __shared__ unsigned short Ks[8 * 544];    // 64 rows, block-padded
    __shared__ unsigned short Vs[8 * 544];    // Vs[d][kk], block-padded
    __shared__ unsigned short Ps[4][16][72];  // per-wave staging [query][key|d]

    int t = threadIdx.x;
    int w = t >> 6, lane = t & 63;
    int q16 = lane & 15, quad = lane >> 4;
    int bh = blockIdx.y, b = bh >> 4, h = bh & 15;
    int s0 = blockIdx.x * 64;

    // stage Q tile (wave w -> 8-row blocks 2w, 2w+1)
    const unsigned short* qg = q + ((size_t)bh * S_ + s0) * HD_;
    gld_lds16(qg + (2 * w) * 512 + lane * 8, &Ks[(2 * w) * 544]);
    gld_lds16(qg + (2 * w + 1) * 512 + lane * 8, &Ks[(2 * w + 1) * 544]);
    __syncthreads();
    int qrow = TBLK(16 * w + q16);
    short8 qf0 = *(const short8*)&Ks[qrow + quad * 8];
    short8 qf1 = *(const short8*)&Ks[qrow + 32 + quad * 8];

    // O^T accumulator: acc_o[nd][i] = O^T[d=16*nd+quad*4+i][query=16w+q16]
    floatx4 acc_o[4];
    float m_i = -3.0e38f, l_i = 0.f;    // per-lane: query 16w+q16
    #pragma unroll
    for (int i = 0; i < 4; ++i) acc_o[i] = (floatx4){0.f, 0.f, 0.f, 0.f};

    const unsigned short* kg = k + (size_t)bh * S_ * HD_;        // tile kt: += 4096
    const unsigned short* vg = vt + (size_t)bh * 64 * S_;        // tile kt: += 64
    int vsrc = (16 * w + (lane >> 3)) * S_ + (lane & 7) * 8;

    for (int kt = 0; kt < S_ / 64; ++kt) {
        __syncthreads();   // all waves done reading Ks/Vs (and Q frags, iter 0)
        gld_lds16(kg + (2 * w) * 512 + lane * 8, &Ks[(2 * w) * 544]);
        gld_lds16(kg + (2 * w + 1) * 512 + lane * 8, &Ks[(2 * w + 1) * 544]);
        gld_lds16(vg + vsrc, &Vs[(2 * w) * 544]);
        gld_lds16(vg + vsrc + 8 * S_, &Vs[(2 * w + 1) * 544]);
        kg += 64 * HD_;
        vg += 64;
        __syncthreads();

        // S^T tiles: sc[nk][i] = S^T[key=16nk+quad*4+i][query=16w+q16]
        floatx4 sc[4];
        #pragma unroll
        for (int nk = 0; nk < 4; ++nk) sc[nk] = (floatx4){0.f, 0.f, 0.f, 0.f};
        #pragma unroll
        for (int nk = 0; nk < 4; ++nk) {
            int krow = TBLK(16 * nk + q16);
            short8 kf0 = *(const short8*)&Ks[krow + quad * 8];
            short8 kf1 = *(const short8*)&Ks[krow + 32 + quad * 8];
            sc[nk] = __builtin_amdgcn_mfma_f32_16x16x32_bf16(kf0, qf0, sc[nk], 0, 0, 0);
            sc[nk] = __builtin_amdgcn_mfma_f32_16x16x32_bf16(kf1, qf1, sc[nk], 0, 0, 0);
        }

        // max over this lane's 16 keys, then across quads (xor 16, 32)
        float mx0 = fmaxf(fmaxf(sc[0][0], sc[0][1]), fmaxf(sc[0][2], sc[0][3]));
        float mx1 = fmaxf(fmaxf(sc[1][0], sc[1][1]), fmaxf(sc[1][2], sc[1][3]));
        float mx2 = fmaxf(fmaxf(sc[2][0], sc[2][1]), fmaxf(sc[2][2], sc[2][3]));
        float mx3 = fmaxf(fmaxf(sc[3][0], sc[3][1]), fmaxf(sc[3][2], sc[3][3]));
        float mx = fmaxf(fmaxf(mx0, mx1), fmaxf(mx2, mx3));
        mx = fmaxf(mx, __shfl_xor(mx, 16));
        mx = fmaxf(mx, __shfl_xor(mx, 32));
        float mnew = fmaxf(m_i, mx);
        float alpha = exp2f(m_i - mnew);
        m_i = mnew;

        // p = exp2(s - m); packed bf16 pairs -> one b64 write per nk
        float rs = 0.f;
        #pragma unroll
        for (int nk = 0; nk < 4; ++nk) {
            float p0 = exp2f(sc[nk][0] - mnew);
            float p1 = exp2f(sc[nk][1] - mnew);
            float p2 = exp2f(sc[nk][2] - mnew);
            float p3 = exp2f(sc[nk][3] - mnew);
            rs += (p0 + p1) + (p2 + p3);
            uint2 pk;
            pk.x = pk_bf16(p0, p1);
            pk.y = pk_bf16(p2, p3);
            *(uint2*)&Ps[w][q16][16 * nk + quad * 4] = pk;
        }
        rs += __shfl_xor(rs, 16);
        rs += __shfl_xor(rs, 32);
        l_i = l_i * alpha + rs;

        #pragma unroll
        for (int nd = 0; nd < 4; ++nd) acc_o[nd] = acc_o[nd] * alpha;

        // fence: P writes must not be reordered vs the P fragment reads below
        __asm__ __volatile__("" ::: "memory");

        // O^T += V^T @ P   (A: Vs[d][key], B: Ps[query][key])
        #pragma unroll
        for (int ks = 0; ks < 2; ++ks) {
            short8 pf = *(const short8*)&Ps[w][q16][ks * 32 + quad * 8];
            #pragma unroll
            for (int nd = 0; nd < 4; ++nd) {
                short8 vf = *(const short8*)&Vs[TBLK(16 * nd + q16) + ks * 32 + quad * 8];
                acc_o[nd] = __builtin_amdgcn_mfma_f32_16x16x32_bf16(vf, pf, acc_o[nd], 0, 0, 0);
            }
        }
    }

    // epilogue: normalize by own l, transpose O^T->O via per-wave LDS tile
    float inv = 1.f / l_i;
    #pragma unroll
    for (int nd = 0; nd < 4; ++nd) {
        uint2 pk;
        pk.x = pk_bf16(acc_o[nd][0] * inv, acc_o[nd][1] * inv);
        pk.y = pk_bf16(acc_o[nd][2] * inv, acc_o[nd][3] * inv);
        *(uint2*)&Ps[w][q16][16 * nd + quad * 4] = pk;   // O[query q16][d]
    }
    __asm__ __volatile__("" ::: "memory");
    // store: row = query 16w+q16; 8 chunks of 8 bf16; quad owns chunks 2q,2q+1
    unsigned short* og = o + ((size_t)(b * S_ + s0 + 16 * w + q16)) * H_ + h * HD_;
    #pragma unroll
    for (int i = 0; i < 2; ++i) {
        int c = quad * 2 + i;          // 0..7
        *(short8*)(og + c * 8) = *(const short8*)&Ps[w][q16][c * 8];
    }
}

// ---------------------------------------------------------------------------
extern "C" void kernel_launch(void* const* d_in, const int* in_sizes, int n_in,
                              void* d_out, int out_size, void* d_ws, size_t ws_size,
                              hipStream_t stream)
{
    const float* x     = (const float*)d_in[0];
    const float* ada   = (const float*)d_in[1];
    const float* freqs = (const float*)d_in[2];
    const float* w_qkv = (const float*)d_in[3];
    const float* w_o   = (const float*)d_in[4];
    const float* ln_w  = (const float*)d_in[5];
    const float* mod_w = (const float*)d_in[6];
    const float* mod_b = (const float*)d_in[7];
    const float* qn_w  = (const float*)d_in[8];
    const float* kn_w  = (const float*)d_in[9];
    float* out = (float*)d_out;

    float* ws  = (float*)d_ws;
    float* mod = ws;                                    // 6144 f (pad to 8192)
    float* qkv = mod + 8192;                            // B*S*3H f
    unsigned short* hb    = (unsigned short*)(qkv + (size_t)B_ * S_ * H3_);
    unsigned short* qb    = hb + (size_t)B_ * S_ * H_;
    unsigned short* kb    = qb + (size_t)B_ * S_ * H_;
    unsigned short* vtb   = kb + (size_t)B_ * S_ * H_;
    unsigned short* ob    = vtb + (size_t)B_ * S_ * H_;
    unsigned short* wqkvb = ob + (size_t)B_ * S_ * H_;
    unsigned short* wob   = wqkvb + (size_t)H3_ * H_;

    cast_bf16_kernel<<<H3_ * H_ / (8 * 256), 256, 0, stream>>>(w_qkv, wqkvb, H3_ * H_);
    cast_bf16_kernel<<<H_ * H_ / (8 * 256), 256, 0, stream>>>(w_o, wob, H_ * H_);
    mod_gemv_kernel<<<B_ * H3_ / 4, 256, 0, stream>>>(ada, mod_w, mod_b, mod);
    ln_mod_kernel<<<B_ * S_, 256, 0, stream>>>(x, ln_w, mod, hb);
    gemm_bt_bf16_kernel<<<dim3(H3_ / 128, B_ * S_ / 128), 256, 0, stream>>>(
        hb, wqkvb, qkv, B_ * S_, H3_, H_, nullptr, 0, 0);
    qk_ln_rope_kernel<<<B_ * NH_ * S_ / 64, 256, 0, stream>>>(
        qkv, freqs, qn_w, kn_w, qb, kb, vtb);
    attn_mfma_kernel<<<dim3(S_ / 64, B_ * NH_), 256, 0, stream>>>(qb, kb, vtb, ob);
    gemm_bt_bf16_kernel<<<dim3(H_ / 128, B_ * S_ / 128), 256, 0, stream>>>(
        ob, wob, out, B_ * S_, H_, H_, mod + 2 * H_, H3_, 11);
}

// Round 8
// 283.288 us; speedup vs baseline: 4.0053x; 1.0656x over previous
//
#include <hip/hip_runtime.h>
#include <hip/hip_bf16.h>
#include <math.h>

// Problem constants
#define B_ 2
#define S_ 2048
#define H_ 1024
#define A_ 1024
#define NH_ 16
#define HD_ 64
#define H3_ 3072
#define EPS_ 1e-5f

typedef __attribute__((ext_vector_type(8))) short short8;   // 8 bf16 in 4 VGPRs
typedef __attribute__((ext_vector_type(4))) float floatx4;  // MFMA accumulator

__device__ inline unsigned short f2bf(float x) {
    union { float f; unsigned u; } v; v.f = x;
    unsigned r = v.u + 0x7fffu + ((v.u >> 16) & 1u);   // RNE
    return (unsigned short)(r >> 16);
}

// packed f32x2 -> bf16x2 (v_cvt_pk_bf16_f32 on gfx950)
__device__ inline unsigned pk_bf16(float a, float b) {
    union { __hip_bfloat162 h; unsigned u; } v;
    v.h = __float22bfloat162_rn(make_float2(a, b));
    return v.u;
}

// async global->LDS, 16B per lane; LDS dst must be wave-uniform base + lane*16
__device__ inline void gld_lds16(const void* g, void* l) {
    __builtin_amdgcn_global_load_lds(
        (const __attribute__((address_space(1))) unsigned int*)g,
        (__attribute__((address_space(3))) unsigned int*)l, 16, 0, 0);
}

// block-padded attention tile layout: 8-row blocks (1024 B) + 64 B pad each.
// row r (0..63), 64 ushorts/row: offset = (r>>3)*544 + (r&7)*64   [ushorts]
#define TBLK(r) ((((r) >> 3) * 544) + (((r) & 7) * 64))

// ---------------------------------------------------------------------------
// Kernel 0: fp32 -> bf16 cast (weights), 8 elems/thread
// ---------------------------------------------------------------------------
__global__ __launch_bounds__(256) void cast_bf16_kernel(
    const float* __restrict__ in, unsigned short* __restrict__ out, int n)
{
    int i = (blockIdx.x * 256 + threadIdx.x) * 8;
    if (i >= n) return;
    float4 a = *(const float4*)(in + i);
    float4 b = *(const float4*)(in + i + 4);
    uint4 o;
    o.x = pk_bf16(a.x, a.y);
    o.y = pk_bf16(a.z, a.w);
    o.z = pk_bf16(b.x, b.y);
    o.w = pk_bf16(b.z, b.w);
    *(uint4*)(out + i) = o;
}

// ---------------------------------------------------------------------------
// Kernel 1: mod = silu(ada_cond) @ mod_w^T + mod_b     [B, 3H]
// ---------------------------------------------------------------------------
__global__ __launch_bounds__(256) void mod_gemv_kernel(
    const float* __restrict__ ada, const float* __restrict__ mod_w,
    const float* __restrict__ mod_b, float* __restrict__ mod)
{
    int wid = threadIdx.x >> 6;
    int lane = threadIdx.x & 63;
    int idx = blockIdx.x * 4 + wid;       // 0 .. B*3H-1
    int b = idx / H3_;
    int j = idx % H3_;
    const float* ar = ada + (size_t)b * A_;
    const float* wr = mod_w + (size_t)j * A_;
    float acc = 0.f;
    for (int a = lane; a < A_; a += 64) {
        float av = ar[a];
        float sv = av / (1.f + __expf(-av));   // silu
        acc += sv * wr[a];
    }
    #pragma unroll
    for (int m = 1; m < 64; m <<= 1) acc += __shfl_xor(acc, m);
    if (lane == 0) mod[idx] = acc + mod_b[j];
}

// ---------------------------------------------------------------------------
// Kernel 2: h = layernorm(x)*ln_w * (scale+1) + shift -> bf16  [B,S,H]
// ---------------------------------------------------------------------------
__global__ __launch_bounds__(256) void ln_mod_kernel(
    const float* __restrict__ x, const float* __restrict__ ln_w,
    const float* __restrict__ mod, unsigned short* __restrict__ hout)
{
    int row = blockIdx.x;          // over B*S
    int b = row >> 11;             // row / 2048
    const float* xr = x + (size_t)row * H_;
    int t = threadIdx.x;
    float4 xv = *(const float4*)(xr + t * 4);
    float s1 = xv.x + xv.y + xv.z + xv.w;
    float s2 = xv.x*xv.x + xv.y*xv.y + xv.z*xv.z + xv.w*xv.w;
    #pragma unroll
    for (int m = 1; m < 64; m <<= 1) { s1 += __shfl_xor(s1, m); s2 += __shfl_xor(s2, m); }
    __shared__ float r1[4], r2[4];
    int wid = t >> 6, lane = t & 63;
    if (lane == 0) { r1[wid] = s1; r2[wid] = s2; }
    __syncthreads();
    s1 = r1[0] + r1[1] + r1[2] + r1[3];
    s2 = r2[0] + r2[1] + r2[2] + r2[3];
    float mean = s1 * (1.f / H_);
    float var  = s2 * (1.f / H_) - mean * mean;
    float rstd = rsqrtf(var + EPS_);
    const float* mrow = mod + (size_t)b * H3_;
    float4 wv = *(const float4*)(ln_w + t * 4);
    float4 sc = *(const float4*)(mrow + t * 4);
    float4 sh = *(const float4*)(mrow + H_ + t * 4);
    float4 hv;
    hv.x = (xv.x - mean) * rstd * wv.x * (sc.x + 1.f) + sh.x;
    hv.y = (xv.y - mean) * rstd * wv.y * (sc.y + 1.f) + sh.y;
    hv.z = (xv.z - mean) * rstd * wv.z * (sc.z + 1.f) + sh.z;
    hv.w = (xv.w - mean) * rstd * wv.w * (sc.w + 1.f) + sh.w;
    uint2 o;
    o.x = pk_bf16(hv.x, hv.y);
    o.y = pk_bf16(hv.z, hv.w);
    *(uint2*)(hout + (size_t)row * H_ + t * 4) = o;
}

// ---------------------------------------------------------------------------
// Kernel 3/6: bf16 MFMA GEMM  C[M,N] = A[M,K] @ B[N,K]^T  (m97 structure)
// ---------------------------------------------------------------------------
__global__ __launch_bounds__(256) void gemm_bt_bf16_kernel(
    const unsigned short* __restrict__ A, const unsigned short* __restrict__ Bm,
    float* __restrict__ C, int M, int N, int K,
    const float* __restrict__ gate, int gate_stride, int batch_shift)
{
    __shared__ unsigned short As[128 * 32];
    __shared__ unsigned short Bs[128 * 32];
    int t = threadIdx.x;
    int w = t >> 6, lane = t & 63;
    int q16 = lane & 15, quad = lane >> 4;
    int wm = w >> 1, wn = w & 1;
    int m0 = blockIdx.y * 128, n0 = blockIdx.x * 128;

    int srow = (w << 5) + (lane >> 2);
    int soff = (lane & 3) << 3;                       // element offset in row
    const unsigned short* ga = A + (size_t)(m0 + srow) * K + soff;
    const unsigned short* gb = Bm + (size_t)(n0 + srow) * K + soff;
    unsigned short* la0 = As + (w << 5) * 32;
    unsigned short* la1 = la0 + 16 * 32;
    unsigned short* lb0 = Bs + (w << 5) * 32;
    unsigned short* lb1 = lb0 + 16 * 32;

    floatx4 acc[4][4];
    #pragma unroll
    for (int mt = 0; mt < 4; ++mt)
        #pragma unroll
        for (int nt = 0; nt < 4; ++nt)
            acc[mt][nt] = (floatx4){0.f, 0.f, 0.f, 0.f};

    int a_row = wm * 64 + q16;
    int b_row = wn * 64 + q16;

    for (int kt = 0; kt < K; kt += 32) {
        __syncthreads();
        gld_lds16(ga, la0);
        gld_lds16(ga + (size_t)16 * K, la1);
        gld_lds16(gb, lb0);
        gld_lds16(gb + (size_t)16 * K, lb1);
        ga += 32; gb += 32;
        __syncthreads();

        short8 af[4], bf[4];
        #pragma unroll
        for (int mt = 0; mt < 4; ++mt)
            af[mt] = *(const short8*)&As[(a_row + mt * 16) * 32 + quad * 8];
        #pragma unroll
        for (int nt = 0; nt < 4; ++nt)
            bf[nt] = *(const short8*)&Bs[(b_row + nt * 16) * 32 + quad * 8];
        #pragma unroll
        for (int mt = 0; mt < 4; ++mt)
            #pragma unroll
            for (int nt = 0; nt < 4; ++nt)
                acc[mt][nt] = __builtin_amdgcn_mfma_f32_16x16x32_bf16(
                    af[mt], bf[nt], acc[mt][nt], 0, 0, 0);
    }

    #pragma unroll
    for (int mt = 0; mt < 4; ++mt) {
        #pragma unroll
        for (int i = 0; i < 4; ++i) {
            int m = m0 + wm * 64 + mt * 16 + quad * 4 + i;
            float* crow = C + (size_t)m * N;
            const float* grow = gate ? gate + (size_t)(m >> batch_shift) * gate_stride
                                     : nullptr;
            #pragma unroll
            for (int nt = 0; nt < 4; ++nt) {
                int n = n0 + wn * 64 + nt * 16 + q16;
                float v = acc[mt][nt][i];
                if (gate) v *= grow[n];
                crow[n] = v;
            }
        }
    }
}

// ---------------------------------------------------------------------------
// Kernel 4: per-head QK layernorm + RoPE; emit bf16 q,k [bh,S,64]
// (q pre-scaled by log2(e)/8 for exp2-domain softmax) and vt [bh,64,S].
// ---------------------------------------------------------------------------
__global__ __launch_bounds__(256) void qk_ln_rope_kernel(
    const float* __restrict__ qkv, const float* __restrict__ freqs,
    const float* __restrict__ qn_w, const float* __restrict__ kn_w,
    unsigned short* __restrict__ qout, unsigned short* __restrict__ kout,
    unsigned short* __restrict__ vtout)
{
    __shared__ unsigned short vt_lds[64][72];
    int t = threadIdx.x;
    int w = t >> 6, lane = t & 63;
    int bh = blockIdx.x >> 5;          // 32 s-blocks per bh
    int sblk = blockIdx.x & 31;
    int h = bh & (NH_ - 1);
    int b = bh >> 4;

    float qnw = qn_w[lane], knw = kn_w[lane];

    for (int it = 0; it < 16; ++it) {
        int s_local = w * 16 + it;
        int s = sblk * 64 + s_local;
        const float* base = qkv + ((size_t)(b * S_ + s)) * H3_;
        float qv = base[h * HD_ + lane];
        float kv = base[H_ + h * HD_ + lane];
        float vv = base[2 * H_ + h * HD_ + lane];

        float qs1 = qv, qs2 = qv * qv, ks1 = kv, ks2 = kv * kv;
        #pragma unroll
        for (int m = 1; m < 64; m <<= 1) {
            qs1 += __shfl_xor(qs1, m); qs2 += __shfl_xor(qs2, m);
            ks1 += __shfl_xor(ks1, m); ks2 += __shfl_xor(ks2, m);
        }
        float qm = qs1 * (1.f / 64), qvar = qs2 * (1.f / 64) - qm * qm;
        float km = ks1 * (1.f / 64), kvar = ks2 * (1.f / 64) - km * km;
        qv = (qv - qm) * rsqrtf(qvar + EPS_) * qnw;
        kv = (kv - km) * rsqrtf(kvar + EPS_) * knw;

        float f0 = freqs[(size_t)s * 64 + (lane >> 1) * 2 + 0];
        float f1 = freqs[(size_t)s * 64 + (lane >> 1) * 2 + 1];
        float qp = __shfl_xor(qv, 1);
        float kp = __shfl_xor(kv, 1);
        float qr = (lane & 1) ? (qv * f0 + qp * f1) : (qv * f0 - qp * f1);
        float kr = (lane & 1) ? (kv * f0 + kp * f1) : (kv * f0 - kp * f1);

        size_t o = ((size_t)bh * S_ + s) * HD_ + lane;
        qout[o] = f2bf(qr * 0.1803368801111244f);  // (1/8)*log2(e)
        kout[o] = f2bf(kr);
        vt_lds[lane][s_local] = f2bf(vv);
    }
    __syncthreads();
    for (int i = t; i < 512; i += 256) {
        int r = i >> 3, c8 = i & 7;
        *(uint4*)(vtout + ((size_t)bh * 64 + r) * S_ + sblk * 64 + c8 * 8) =
            *(const uint4*)&vt_lds[r][c8 * 8];
    }
}

// ---------------------------------------------------------------------------
// Kernel 5: bf16-MFMA flash attention, STATIC-shift softmax.
// Q,K layernormed => |q.k/8 * log2e| <= 11.7 < 12 (Cauchy-Schwarz with exact
// LN norms), so softmax uses a FIXED shift of 12: no running max, no alpha
// rescale, no cross-lane reductions. l is computed by an extra ones-row MFMA
// (matrix pipe has slack); its internal K-reduction makes l per-lane exact.
// ---------------------------------------------------------------------------
__global__ __launch_bounds__(256) void attn_mfma_kernel(
    const unsigned short* __restrict__ q, const unsigned short* __restrict__ k,
    const unsigned short* __restrict__ vt, unsigned short* __restrict__ o)
{
    __shared__ unsigned short Ks[8 * 544];    // 64 rows, block-padded
    __shared__ unsigned short Vs[8 * 544];    // Vs[d][kk], block-padded
    __shared__ unsigned short Ps[4][16][72];  // per-wave staging [query][key|d]

    int t = threadIdx.x;
    int w = t >> 6, lane = t & 63;
    int q16 = lane & 15, quad = lane >> 4;
    int bh = blockIdx.y, b = bh >> 4, h = bh & 15;
    int s0 = blockIdx.x * 64;

    // stage Q tile (wave w -> 8-row blocks 2w, 2w+1)
    const unsigned short* qg = q + ((size_t)bh * S_ + s0) * HD_;
    gld_lds16(qg + (2 * w) * 512 + lane * 8, &Ks[(2 * w) * 544]);
    gld_lds16(qg + (2 * w + 1) * 512 + lane * 8, &Ks[(2 * w + 1) * 544]);
    __syncthreads();
    int qrow = TBLK(16 * w + q16);
    short8 qf0 = *(const short8*)&Ks[qrow + quad * 8];
    short8 qf1 = *(const short8*)&Ks[qrow + 32 + quad * 8];

    // ones A-fragment (bf16 1.0 = 0x3F80) for the l-row MFMA
    short8 ones8;
    #pragma unroll
    for (int i = 0; i < 8; ++i) ones8[i] = (short)0x3F80;

    // O^T accumulator: acc_o[nd][i] = O^T[d=16*nd+quad*4+i][query=16w+q16]
    floatx4 acc_o[4];
    floatx4 acc_l = (floatx4){0.f, 0.f, 0.f, 0.f};
    #pragma unroll
    for (int i = 0; i < 4; ++i) acc_o[i] = (floatx4){0.f, 0.f, 0.f, 0.f};

    const unsigned short* kg = k + (size_t)bh * S_ * HD_;        // tile kt: += 4096
    const unsigned short* vg = vt + (size_t)bh * 64 * S_;        // tile kt: += 64
    int vsrc = (16 * w + (lane >> 3)) * S_ + (lane & 7) * 8;

    for (int kt = 0; kt < S_ / 64; ++kt) {
        __syncthreads();   // all waves done reading Ks/Vs (and Q frags, iter 0)
        gld_lds16(kg + (2 * w) * 512 + lane * 8, &Ks[(2 * w) * 544]);
        gld_lds16(kg + (2 * w + 1) * 512 + lane * 8, &Ks[(2 * w + 1) * 544]);
        gld_lds16(vg + vsrc, &Vs[(2 * w) * 544]);
        gld_lds16(vg + vsrc + 8 * S_, &Vs[(2 * w + 1) * 544]);
        kg += 64 * HD_;
        vg += 64;
        __syncthreads();

        // S^T tiles (C-init = -12: static softmax shift folded into MFMA)
        floatx4 sc[4];
        #pragma unroll
        for (int nk = 0; nk < 4; ++nk) sc[nk] = (floatx4){-12.f, -12.f, -12.f, -12.f};
        #pragma unroll
        for (int nk = 0; nk < 4; ++nk) {
            int krow = TBLK(16 * nk + q16);
            short8 kf0 = *(const short8*)&Ks[krow + quad * 8];
            short8 kf1 = *(const short8*)&Ks[krow + 32 + quad * 8];
            sc[nk] = __builtin_amdgcn_mfma_f32_16x16x32_bf16(kf0, qf0, sc[nk], 0, 0, 0);
            sc[nk] = __builtin_amdgcn_mfma_f32_16x16x32_bf16(kf1, qf1, sc[nk], 0, 0, 0);
        }

        // p = exp2(s - 12); packed bf16 pairs -> one b64 write per nk
        #pragma unroll
        for (int nk = 0; nk < 4; ++nk) {
            float p0 = exp2f(sc[nk][0]);
            float p1 = exp2f(sc[nk][1]);
            float p2 = exp2f(sc[nk][2]);
            float p3 = exp2f(sc[nk][3]);
            uint2 pk;
            pk.x = pk_bf16(p0, p1);
            pk.y = pk_bf16(p2, p3);
            *(uint2*)&Ps[w][q16][16 * nk + quad * 4] = pk;
        }

        // fence: P writes must not be reordered vs the P fragment reads below
        __asm__ __volatile__("" ::: "memory");

        // O^T += V^T @ P ; l += ones @ P (internal K-reduction gives row sums)
        #pragma unroll
        for (int ks = 0; ks < 2; ++ks) {
            short8 pf = *(const short8*)&Ps[w][q16][ks * 32 + quad * 8];
            acc_l = __builtin_amdgcn_mfma_f32_16x16x32_bf16(ones8, pf, acc_l, 0, 0, 0);
            #pragma unroll
            for (int nd = 0; nd < 4; ++nd) {
                short8 vf = *(const short8*)&Vs[TBLK(16 * nd + q16) + ks * 32 + quad * 8];
                acc_o[nd] = __builtin_amdgcn_mfma_f32_16x16x32_bf16(vf, pf, acc_o[nd], 0, 0, 0);
            }
        }
    }

    // epilogue: l = acc_l[0] (all 4 rows identical); no cross-lane reduction
    float inv = 1.f / acc_l[0];
    #pragma unroll
    for (int nd = 0; nd < 4; ++nd) {
        uint2 pk;
        pk.x = pk_bf16(acc_o[nd][0] * inv, acc_o[nd][1] * inv);
        pk.y = pk_bf16(acc_o[nd][2] * inv, acc_o[nd][3] * inv);
        *(uint2*)&Ps[w][q16][16 * nd + quad * 4] = pk;   // O[query q16][d]
    }
    __asm__ __volatile__("" ::: "memory");
    // store: row = query 16w+q16; 8 chunks of 8 bf16; quad owns chunks 2q,2q+1
    unsigned short* og = o + ((size_t)(b * S_ + s0 + 16 * w + q16)) * H_ + h * HD_;
    #pragma unroll
    for (int i = 0; i < 2; ++i) {
        int c = quad * 2 + i;          // 0..7
        *(short8*)(og + c * 8) = *(const short8*)&Ps[w][q16][c * 8];
    }
}

// ---------------------------------------------------------------------------
extern "C" void kernel_launch(void* const* d_in, const int* in_sizes, int n_in,
                              void* d_out, int out_size, void* d_ws, size_t ws_size,
                              hipStream_t stream)
{
    const float* x     = (const float*)d_in[0];
    const float* ada   = (const float*)d_in[1];
    const float* freqs = (const float*)d_in[2];
    const float* w_qkv = (const float*)d_in[3];
    const float* w_o   = (const float*)d_in[4];
    const float* ln_w  = (const float*)d_in[5];
    const float* mod_w = (const float*)d_in[6];
    const float* mod_b = (const float*)d_in[7];
    const float* qn_w  = (const float*)d_in[8];
    const float* kn_w  = (const float*)d_in[9];
    float* out = (float*)d_out;

    float* ws  = (float*)d_ws;
    float* mod = ws;                                    // 6144 f (pad to 8192)
    float* qkv = mod + 8192;                            // B*S*3H f
    unsigned short* hb    = (unsigned short*)(qkv + (size_t)B_ * S_ * H3_);
    unsigned short* qb    = hb + (size_t)B_ * S_ * H_;
    unsigned short* kb    = qb + (size_t)B_ * S_ * H_;
    unsigned short* vtb   = kb + (size_t)B_ * S_ * H_;
    unsigned short* ob    = vtb + (size_t)B_ * S_ * H_;
    unsigned short* wqkvb = ob + (size_t)B_ * S_ * H_;
    unsigned short* wob   = wqkvb + (size_t)H3_ * H_;

    cast_bf16_kernel<<<H3_ * H_ / (8 * 256), 256, 0, stream>>>(w_qkv, wqkvb, H3_ * H_);
    cast_bf16_kernel<<<H_ * H_ / (8 * 256), 256, 0, stream>>>(w_o, wob, H_ * H_);
    mod_gemv_kernel<<<B_ * H3_ / 4, 256, 0, stream>>>(ada, mod_w, mod_b, mod);
    ln_mod_kernel<<<B_ * S_, 256, 0, stream>>>(x, ln_w, mod, hb);
    gemm_bt_bf16_kernel<<<dim3(H3_ / 128, B_ * S_ / 128), 256, 0, stream>>>(
        hb, wqkvb, qkv, B_ * S_, H3_, H_, nullptr, 0, 0);
    qk_ln_rope_kernel<<<B_ * NH_ * S_ / 64, 256, 0, stream>>>(
        qkv, freqs, qn_w, kn_w, qb, kb, vtb);
    attn_mfma_kernel<<<dim3(S_ / 64, B_ * NH_), 256, 0, stream>>>(qb, kb, vtb, ob);
    gemm_bt_bf16_kernel<<<dim3(H_ / 128, B_ * S_ / 128), 256, 0, stream>>>(
        ob, wob, out, B_ * S_, H_, H_, mod + 2 * H_, H3_, 11);
}

// Round 9
// 275.694 us; speedup vs baseline: 4.1157x; 1.0275x over previous
//
#include <hip/hip_runtime.h>
#include <hip/hip_bf16.h>
#include <math.h>

// Problem constants
#define B_ 2
#define S_ 2048
#define H_ 1024
#define A_ 1024
#define NH_ 16
#define HD_ 64
#define H3_ 3072
#define EPS_ 1e-5f

typedef __attribute__((ext_vector_type(8))) short short8;   // 8 bf16 in 4 VGPRs
typedef __attribute__((ext_vector_type(4))) float floatx4;  // MFMA accumulator

__device__ inline unsigned short f2bf(float x) {
    union { float f; unsigned u; } v; v.f = x;
    unsigned r = v.u + 0x7fffu + ((v.u >> 16) & 1u);   // RNE
    return (unsigned short)(r >> 16);
}

__device__ inline float bf2f(unsigned short u) {
    union { unsigned u; float f; } v; v.u = ((unsigned)u) << 16;
    return v.f;
}

// packed f32x2 -> bf16x2 (v_cvt_pk_bf16_f32 on gfx950)
__device__ inline unsigned pk_bf16(float a, float b) {
    union { __hip_bfloat162 h; unsigned u; } v;
    v.h = __float22bfloat162_rn(make_float2(a, b));
    return v.u;
}

// async global->LDS, 16B per lane; LDS dst must be wave-uniform base + lane*16
__device__ inline void gld_lds16(const void* g, void* l) {
    __builtin_amdgcn_global_load_lds(
        (const __attribute__((address_space(1))) unsigned int*)g,
        (__attribute__((address_space(3))) unsigned int*)l, 16, 0, 0);
}

// block-padded attention tile layout: 8-row blocks (1024 B) + 64 B pad each.
// row r (0..63), 64 ushorts/row: offset = (r>>3)*544 + (r&7)*64   [ushorts]
#define TBLK(r) ((((r) >> 3) * 544) + (((r) & 7) * 64))

// ---------------------------------------------------------------------------
// Kernel 0: fp32 -> bf16 cast (weights), 8 elems/thread
// ---------------------------------------------------------------------------
__global__ __launch_bounds__(256) void cast_bf16_kernel(
    const float* __restrict__ in, unsigned short* __restrict__ out, int n)
{
    int i = (blockIdx.x * 256 + threadIdx.x) * 8;
    if (i >= n) return;
    float4 a = *(const float4*)(in + i);
    float4 b = *(const float4*)(in + i + 4);
    uint4 o;
    o.x = pk_bf16(a.x, a.y);
    o.y = pk_bf16(a.z, a.w);
    o.z = pk_bf16(b.x, b.y);
    o.w = pk_bf16(b.z, b.w);
    *(uint4*)(out + i) = o;
}

// ---------------------------------------------------------------------------
// Kernel 1: mod = silu(ada_cond) @ mod_w^T + mod_b     [B, 3H]
// ---------------------------------------------------------------------------
__global__ __launch_bounds__(256) void mod_gemv_kernel(
    const float* __restrict__ ada, const float* __restrict__ mod_w,
    const float* __restrict__ mod_b, float* __restrict__ mod)
{
    int wid = threadIdx.x >> 6;
    int lane = threadIdx.x & 63;
    int idx = blockIdx.x * 4 + wid;       // 0 .. B*3H-1
    int b = idx / H3_;
    int j = idx % H3_;
    const float* ar = ada + (size_t)b * A_;
    const float* wr = mod_w + (size_t)j * A_;
    float acc = 0.f;
    for (int a = lane; a < A_; a += 64) {
        float av = ar[a];
        float sv = av / (1.f + __expf(-av));   // silu
        acc += sv * wr[a];
    }
    #pragma unroll
    for (int m = 1; m < 64; m <<= 1) acc += __shfl_xor(acc, m);
    if (lane == 0) mod[idx] = acc + mod_b[j];
}

// ---------------------------------------------------------------------------
// Kernel 2: h = layernorm(x)*ln_w * (scale+1) + shift -> bf16  [B,S,H]
// ---------------------------------------------------------------------------
__global__ __launch_bounds__(256) void ln_mod_kernel(
    const float* __restrict__ x, const float* __restrict__ ln_w,
    const float* __restrict__ mod, unsigned short* __restrict__ hout)
{
    int row = blockIdx.x;          // over B*S
    int b = row >> 11;             // row / 2048
    const float* xr = x + (size_t)row * H_;
    int t = threadIdx.x;
    float4 xv = *(const float4*)(xr + t * 4);
    float s1 = xv.x + xv.y + xv.z + xv.w;
    float s2 = xv.x*xv.x + xv.y*xv.y + xv.z*xv.z + xv.w*xv.w;
    #pragma unroll
    for (int m = 1; m < 64; m <<= 1) { s1 += __shfl_xor(s1, m); s2 += __shfl_xor(s2, m); }
    __shared__ float r1[4], r2[4];
    int wid = t >> 6, lane = t & 63;
    if (lane == 0) { r1[wid] = s1; r2[wid] = s2; }
    __syncthreads();
    s1 = r1[0] + r1[1] + r1[2] + r1[3];
    s2 = r2[0] + r2[1] + r2[2] + r2[3];
    float mean = s1 * (1.f / H_);
    float var  = s2 * (1.f / H_) - mean * mean;
    float rstd = rsqrtf(var + EPS_);
    const float* mrow = mod + (size_t)b * H3_;
    float4 wv = *(const float4*)(ln_w + t * 4);
    float4 sc = *(const float4*)(mrow + t * 4);
    float4 sh = *(const float4*)(mrow + H_ + t * 4);
    float4 hv;
    hv.x = (xv.x - mean) * rstd * wv.x * (sc.x + 1.f) + sh.x;
    hv.y = (xv.y - mean) * rstd * wv.y * (sc.y + 1.f) + sh.y;
    hv.z = (xv.z - mean) * rstd * wv.z * (sc.z + 1.f) + sh.z;
    hv.w = (xv.w - mean) * rstd * wv.w * (sc.w + 1.f) + sh.w;
    uint2 o;
    o.x = pk_bf16(hv.x, hv.y);
    o.y = pk_bf16(hv.z, hv.w);
    *(uint2*)(hout + (size_t)row * H_ + t * 4) = o;
}

// ---------------------------------------------------------------------------
// Kernel 3/6: bf16 MFMA GEMM  C[M,N] = A[M,K] @ B[N,K]^T  (m97 structure)
// out_bf16: C written as bf16 (ushort) instead of fp32.
// ---------------------------------------------------------------------------
__global__ __launch_bounds__(256) void gemm_bt_bf16_kernel(
    const unsigned short* __restrict__ A, const unsigned short* __restrict__ Bm,
    void* __restrict__ C, int M, int N, int K, int out_bf16,
    const float* __restrict__ gate, int gate_stride, int batch_shift)
{
    __shared__ unsigned short As[128 * 32];
    __shared__ unsigned short Bs[128 * 32];
    int t = threadIdx.x;
    int w = t >> 6, lane = t & 63;
    int q16 = lane & 15, quad = lane >> 4;
    int wm = w >> 1, wn = w & 1;
    int m0 = blockIdx.y * 128, n0 = blockIdx.x * 128;

    int srow = (w << 5) + (lane >> 2);
    int soff = (lane & 3) << 3;                       // element offset in row
    const unsigned short* ga = A + (size_t)(m0 + srow) * K + soff;
    const unsigned short* gb = Bm + (size_t)(n0 + srow) * K + soff;
    unsigned short* la0 = As + (w << 5) * 32;
    unsigned short* la1 = la0 + 16 * 32;
    unsigned short* lb0 = Bs + (w << 5) * 32;
    unsigned short* lb1 = lb0 + 16 * 32;

    floatx4 acc[4][4];
    #pragma unroll
    for (int mt = 0; mt < 4; ++mt)
        #pragma unroll
        for (int nt = 0; nt < 4; ++nt)
            acc[mt][nt] = (floatx4){0.f, 0.f, 0.f, 0.f};

    int a_row = wm * 64 + q16;
    int b_row = wn * 64 + q16;

    for (int kt = 0; kt < K; kt += 32) {
        __syncthreads();
        gld_lds16(ga, la0);
        gld_lds16(ga + (size_t)16 * K, la1);
        gld_lds16(gb, lb0);
        gld_lds16(gb + (size_t)16 * K, lb1);
        ga += 32; gb += 32;
        __syncthreads();

        short8 af[4], bf[4];
        #pragma unroll
        for (int mt = 0; mt < 4; ++mt)
            af[mt] = *(const short8*)&As[(a_row + mt * 16) * 32 + quad * 8];
        #pragma unroll
        for (int nt = 0; nt < 4; ++nt)
            bf[nt] = *(const short8*)&Bs[(b_row + nt * 16) * 32 + quad * 8];
        #pragma unroll
        for (int mt = 0; mt < 4; ++mt)
            #pragma unroll
            for (int nt = 0; nt < 4; ++nt)
                acc[mt][nt] = __builtin_amdgcn_mfma_f32_16x16x32_bf16(
                    af[mt], bf[nt], acc[mt][nt], 0, 0, 0);
    }

    #pragma unroll
    for (int mt = 0; mt < 4; ++mt) {
        #pragma unroll
        for (int i = 0; i < 4; ++i) {
            int m = m0 + wm * 64 + mt * 16 + quad * 4 + i;
            const float* grow = gate ? gate + (size_t)(m >> batch_shift) * gate_stride
                                     : nullptr;
            #pragma unroll
            for (int nt = 0; nt < 4; ++nt) {
                int n = n0 + wn * 64 + nt * 16 + q16;
                float v = acc[mt][nt][i];
                if (gate) v *= grow[n];
                if (out_bf16)
                    ((unsigned short*)C)[(size_t)m * N + n] =
                        (unsigned short)pk_bf16(v, 0.f);
                else
                    ((float*)C)[(size_t)m * N + n] = v;
            }
        }
    }
}

// ---------------------------------------------------------------------------
// Kernel 4: per-head QK layernorm + RoPE; reads bf16 qkv; emits bf16 q,k
// [bh,S,64] (q pre-scaled by log2(e)/8) and vt [bh,64,S].
// ---------------------------------------------------------------------------
__global__ __launch_bounds__(256) void qk_ln_rope_kernel(
    const unsigned short* __restrict__ qkv, const float* __restrict__ freqs,
    const float* __restrict__ qn_w, const float* __restrict__ kn_w,
    unsigned short* __restrict__ qout, unsigned short* __restrict__ kout,
    unsigned short* __restrict__ vtout)
{
    __shared__ unsigned short vt_lds[64][72];
    int t = threadIdx.x;
    int w = t >> 6, lane = t & 63;
    int bh = blockIdx.x >> 5;          // 32 s-blocks per bh
    int sblk = blockIdx.x & 31;
    int h = bh & (NH_ - 1);
    int b = bh >> 4;

    float qnw = qn_w[lane], knw = kn_w[lane];

    for (int it = 0; it < 16; ++it) {
        int s_local = w * 16 + it;
        int s = sblk * 64 + s_local;
        const unsigned short* base = qkv + ((size_t)(b * S_ + s)) * H3_;
        float qv = bf2f(base[h * HD_ + lane]);
        float kv = bf2f(base[H_ + h * HD_ + lane]);
        unsigned short vv = base[2 * H_ + h * HD_ + lane];

        float qs1 = qv, qs2 = qv * qv, ks1 = kv, ks2 = kv * kv;
        #pragma unroll
        for (int m = 1; m < 64; m <<= 1) {
            qs1 += __shfl_xor(qs1, m); qs2 += __shfl_xor(qs2, m);
            ks1 += __shfl_xor(ks1, m); ks2 += __shfl_xor(ks2, m);
        }
        float qm = qs1 * (1.f / 64), qvar = qs2 * (1.f / 64) - qm * qm;
        float km = ks1 * (1.f / 64), kvar = ks2 * (1.f / 64) - km * km;
        qv = (qv - qm) * rsqrtf(qvar + EPS_) * qnw;
        kv = (kv - km) * rsqrtf(kvar + EPS_) * knw;

        float f0 = freqs[(size_t)s * 64 + (lane >> 1) * 2 + 0];
        float f1 = freqs[(size_t)s * 64 + (lane >> 1) * 2 + 1];
        float qp = __shfl_xor(qv, 1);
        float kp = __shfl_xor(kv, 1);
        float qr = (lane & 1) ? (qv * f0 + qp * f1) : (qv * f0 - qp * f1);
        float kr = (lane & 1) ? (kv * f0 + kp * f1) : (kv * f0 - kp * f1);

        size_t o = ((size_t)bh * S_ + s) * HD_ + lane;
        qout[o] = f2bf(qr * 0.1803368801111244f);  // (1/8)*log2(e)
        kout[o] = f2bf(kr);
        vt_lds[lane][s_local] = vv;
    }
    __syncthreads();
    for (int i = t; i < 512; i += 256) {
        int r = i >> 3, c8 = i & 7;
        *(uint4*)(vtout + ((size_t)bh * 64 + r) * S_ + sblk * 64 + c8 * 8) =
            *(const uint4*)&vt_lds[r][c8 * 8];
    }
}

// ---------------------------------------------------------------------------
// Kernel 5: bf16-MFMA flash attention, STATIC-shift softmax.
// Q,K layernormed => |q.k/8 * log2e| <= 11.7 < 12 (Cauchy-Schwarz), so
// softmax uses a FIXED shift of 12: no running max, no alpha rescale.
// l via ones-row MFMA. exp2 via raw v_exp_f32 builtin (args in [-24,0]:
// no denormal fixup needed; libm exp2f carries a ~6-op range guard).
// ---------------------------------------------------------------------------
__global__ __launch_bounds__(256) void attn_mfma_kernel(
    const unsigned short* __restrict__ q, const unsigned short* __restrict__ k,
    const unsigned short* __restrict__ vt, unsigned short* __restrict__ o)
{
    __shared__ unsigned short Ks[8 * 544];    // 64 rows, block-padded
    __shared__ unsigned short Vs[8 * 544];    // Vs[d][kk], block-padded
    __shared__ unsigned short Ps[4][16][72];  // per-wave staging [query][key|d]

    int t = threadIdx.x;
    int w = t >> 6, lane = t & 63;
    int q16 = lane & 15, quad = lane >> 4;
    int bh = blockIdx.y, b = bh >> 4, h = bh & 15;
    int s0 = blockIdx.x * 64;

    // stage Q tile (wave w -> 8-row blocks 2w, 2w+1)
    const unsigned short* qg = q + ((size_t)bh * S_ + s0) * HD_;
    gld_lds16(qg + (2 * w) * 512 + lane * 8, &Ks[(2 * w) * 544]);
    gld_lds16(qg + (2 * w + 1) * 512 + lane * 8, &Ks[(2 * w + 1) * 544]);
    __syncthreads();
    int qrow = TBLK(16 * w + q16);
    short8 qf0 = *(const short8*)&Ks[qrow + quad * 8];
    short8 qf1 = *(const short8*)&Ks[qrow + 32 + quad * 8];

    // ones A-fragment (bf16 1.0 = 0x3F80) for the l-row MFMA
    short8 ones8;
    #pragma unroll
    for (int i = 0; i < 8; ++i) ones8[i] = (short)0x3F80;

    // O^T accumulator: acc_o[nd][i] = O^T[d=16*nd+quad*4+i][query=16w+q16]
    floatx4 acc_o[4];
    floatx4 acc_l = (floatx4){0.f, 0.f, 0.f, 0.f};
    #pragma unroll
    for (int i = 0; i < 4; ++i) acc_o[i] = (floatx4){0.f, 0.f, 0.f, 0.f};

    const unsigned short* kg = k + (size_t)bh * S_ * HD_;        // tile kt: += 4096
    const unsigned short* vg = vt + (size_t)bh * 64 * S_;        // tile kt: += 64
    int vsrc = (16 * w + (lane >> 3)) * S_ + (lane & 7) * 8;

    for (int kt = 0; kt < S_ / 64; ++kt) {
        __syncthreads();   // all waves done reading Ks/Vs (and Q frags, iter 0)
        gld_lds16(kg + (2 * w) * 512 + lane * 8, &Ks[(2 * w) * 544]);
        gld_lds16(kg + (2 * w + 1) * 512 + lane * 8, &Ks[(2 * w + 1) * 544]);
        gld_lds16(vg + vsrc, &Vs[(2 * w) * 544]);
        gld_lds16(vg + vsrc + 8 * S_, &Vs[(2 * w + 1) * 544]);
        kg += 64 * HD_;
        vg += 64;
        __syncthreads();

        // S^T tiles (C-init = -12: static softmax shift folded into MFMA)
        floatx4 sc[4];
        #pragma unroll
        for (int nk = 0; nk < 4; ++nk) sc[nk] = (floatx4){-12.f, -12.f, -12.f, -12.f};
        #pragma unroll
        for (int nk = 0; nk < 4; ++nk) {
            int krow = TBLK(16 * nk + q16);
            short8 kf0 = *(const short8*)&Ks[krow + quad * 8];
            short8 kf1 = *(const short8*)&Ks[krow + 32 + quad * 8];
            sc[nk] = __builtin_amdgcn_mfma_f32_16x16x32_bf16(kf0, qf0, sc[nk], 0, 0, 0);
            sc[nk] = __builtin_amdgcn_mfma_f32_16x16x32_bf16(kf1, qf1, sc[nk], 0, 0, 0);
        }

        // p = exp2(s - 12); raw v_exp_f32; packed bf16 pairs -> b64 write
        #pragma unroll
        for (int nk = 0; nk < 4; ++nk) {
            float p0 = __builtin_amdgcn_exp2f(sc[nk][0]);
            float p1 = __builtin_amdgcn_exp2f(sc[nk][1]);
            float p2 = __builtin_amdgcn_exp2f(sc[nk][2]);
            float p3 = __builtin_amdgcn_exp2f(sc[nk][3]);
            uint2 pk;
            pk.x = pk_bf16(p0, p1);
            pk.y = pk_bf16(p2, p3);
            *(uint2*)&Ps[w][q16][16 * nk + quad * 4] = pk;
        }

        // fence: P writes must not be reordered vs the P fragment reads below
        __asm__ __volatile__("" ::: "memory");

        // O^T += V^T @ P ; l += ones @ P (internal K-reduction gives row sums)
        #pragma unroll
        for (int ks = 0; ks < 2; ++ks) {
            short8 pf = *(const short8*)&Ps[w][q16][ks * 32 + quad * 8];
            acc_l = __builtin_amdgcn_mfma_f32_16x16x32_bf16(ones8, pf, acc_l, 0, 0, 0);
            #pragma unroll
            for (int nd = 0; nd < 4; ++nd) {
                short8 vf = *(const short8*)&Vs[TBLK(16 * nd + q16) + ks * 32 + quad * 8];
                acc_o[nd] = __builtin_amdgcn_mfma_f32_16x16x32_bf16(vf, pf, acc_o[nd], 0, 0, 0);
            }
        }
    }

    // epilogue: l = acc_l[0] (all 4 rows identical); no cross-lane reduction
    float inv = 1.f / acc_l[0];
    #pragma unroll
    for (int nd = 0; nd < 4; ++nd) {
        uint2 pk;
        pk.x = pk_bf16(acc_o[nd][0] * inv, acc_o[nd][1] * inv);
        pk.y = pk_bf16(acc_o[nd][2] * inv, acc_o[nd][3] * inv);
        *(uint2*)&Ps[w][q16][16 * nd + quad * 4] = pk;   // O[query q16][d]
    }
    __asm__ __volatile__("" ::: "memory");
    // store: row = query 16w+q16; 8 chunks of 8 bf16; quad owns chunks 2q,2q+1
    unsigned short* og = o + ((size_t)(b * S_ + s0 + 16 * w + q16)) * H_ + h * HD_;
    #pragma unroll
    for (int i = 0; i < 2; ++i) {
        int c = quad * 2 + i;          // 0..7
        *(short8*)(og + c * 8) = *(const short8*)&Ps[w][q16][c * 8];
    }
}

// ---------------------------------------------------------------------------
extern "C" void kernel_launch(void* const* d_in, const int* in_sizes, int n_in,
                              void* d_out, int out_size, void* d_ws, size_t ws_size,
                              hipStream_t stream)
{
    const float* x     = (const float*)d_in[0];
    const float* ada   = (const float*)d_in[1];
    const float* freqs = (const float*)d_in[2];
    const float* w_qkv = (const float*)d_in[3];
    const float* w_o   = (const float*)d_in[4];
    const float* ln_w  = (const float*)d_in[5];
    const float* mod_w = (const float*)d_in[6];
    const float* mod_b = (const float*)d_in[7];
    const float* qn_w  = (const float*)d_in[8];
    const float* kn_w  = (const float*)d_in[9];
    float* out = (float*)d_out;

    float* ws  = (float*)d_ws;
    float* mod = ws;                                    // 6144 f (pad to 8192)
    unsigned short* qkvb  = (unsigned short*)(mod + 8192);   // B*S*3H bf16
    unsigned short* hb    = qkvb + (size_t)B_ * S_ * H3_;
    unsigned short* qb    = hb + (size_t)B_ * S_ * H_;
    unsigned short* kb    = qb + (size_t)B_ * S_ * H_;
    unsigned short* vtb   = kb + (size_t)B_ * S_ * H_;
    unsigned short* ob    = vtb + (size_t)B_ * S_ * H_;
    unsigned short* wqkvb = ob + (size_t)B_ * S_ * H_;
    unsigned short* wob   = wqkvb + (size_t)H3_ * H_;

    cast_bf16_kernel<<<H3_ * H_ / (8 * 256), 256, 0, stream>>>(w_qkv, wqkvb, H3_ * H_);
    cast_bf16_kernel<<<H_ * H_ / (8 * 256), 256, 0, stream>>>(w_o, wob, H_ * H_);
    mod_gemv_kernel<<<B_ * H3_ / 4, 256, 0, stream>>>(ada, mod_w, mod_b, mod);
    ln_mod_kernel<<<B_ * S_, 256, 0, stream>>>(x, ln_w, mod, hb);
    gemm_bt_bf16_kernel<<<dim3(H3_ / 128, B_ * S_ / 128), 256, 0, stream>>>(
        hb, wqkvb, qkvb, B_ * S_, H3_, H_, 1, nullptr, 0, 0);
    qk_ln_rope_kernel<<<B_ * NH_ * S_ / 64, 256, 0, stream>>>(
        qkvb, freqs, qn_w, kn_w, qb, kb, vtb);
    attn_mfma_kernel<<<dim3(S_ / 64, B_ * NH_), 256, 0, stream>>>(qb, kb, vtb, ob);
    gemm_bt_bf16_kernel<<<dim3(H_ / 128, B_ * S_ / 128), 256, 0, stream>>>(
        ob, wob, out, B_ * S_, H_, H_, 0, mod + 2 * H_, H3_, 11);
}